// Round 6
// baseline (1108.507 us; speedup 1.0000x reference)
//
#include <hip/hip_runtime.h>
#include <hip/hip_bf16.h>

#define D 128
#define CAPB 2048   // pairs/CSR capacity per 256-dst bin (mean load ~1300, +20 sigma safe; ovf fallback exact)

typedef __attribute__((ext_vector_type(8))) short bf16x8;
typedef __attribute__((ext_vector_type(4))) float f32x4;

__device__ __forceinline__ void atomAddF(float* p, float v) { unsafeAtomicAdd(p, v); }

__device__ __forceinline__ unsigned short f2bf(float f) {
    __hip_bfloat16 h = __float2bfloat16(f);
    return *reinterpret_cast<unsigned short*>(&h);
}
__device__ __forceinline__ float bf2f(unsigned int u16) {
    unsigned int x = u16 << 16;
    return *reinterpret_cast<float*>(&x);
}

// ---------------- fused cast fp32 -> bf16 for all three node tensors ----------------
__global__ void cast_bf16_3(const float* __restrict__ a, long n4a,
                            const float* __restrict__ b, long n4b,
                            const float* __restrict__ c, long n4c,
                            unsigned short* __restrict__ oa,
                            unsigned short* __restrict__ ob,
                            unsigned short* __restrict__ oc) {
    long i = (long)blockIdx.x * blockDim.x + threadIdx.x;
    const float* in; unsigned short* out; long li;
    if (i < n4a)                { in = a; out = oa; li = i; }
    else if (i < n4a + n4b)     { in = b; out = ob; li = i - n4a; }
    else if (i < n4a + n4b + n4c) { in = c; out = oc; li = i - n4a - n4b; }
    else return;
    float4 v = ((const float4*)in)[li];
    ushort4 o;
    o.x = f2bf(v.x); o.y = f2bf(v.y); o.z = f2bf(v.z); o.w = f2bf(v.w);
    ((ushort4*)out)[li] = o;
}

// ---------------- weights: cast + transpose (Wt[n*128+k] = W[k*128+n]) ----------------
__global__ void prep_weights(const float* __restrict__ Wra, const float* __restrict__ Wrg,
                             const float* __restrict__ Wrt, const float* __restrict__ Wroot_t,
                             const float* __restrict__ Wroot_a, const float* __restrict__ Wroot_g,
                             const float* __restrict__ ba, const float* __restrict__ bg,
                             unsigned short* __restrict__ Wt_adj, unsigned short* __restrict__ Wt_g,
                             unsigned short* __restrict__ Wt_t, unsigned short* __restrict__ Wt_root_t,
                             unsigned short* __restrict__ Wt_sum, float* __restrict__ bsum) {
    int i = blockIdx.x * blockDim.x + threadIdx.x;
    if (i < D * D) {
        int k = i >> 7, n = i & 127;
        int ti = n * D + k;
        Wt_adj[ti]    = f2bf(Wra[i]);
        Wt_g[ti]      = f2bf(Wrg[i]);
        Wt_t[ti]      = f2bf(Wrt[i]);
        Wt_root_t[ti] = f2bf(Wroot_t[i]);
        Wt_sum[ti]    = f2bf(Wroot_a[i] + Wroot_g[i]);
    }
    if (i < D) bsum[i] = ba[i] + bg[i];
}

// ---------------- pass 1: bin edges as packed (src<<8 | dst&255) pairs ----------------
// Slots within a bin fill in arrival order -> consecutive stores to a 64B line happen
// close in time -> L2 write-combines -> streaming writes (vs 120MB of random line flushes
// with the old per-dst bucket scatter). Counters are ~2K hot ints (L2-resident).
__global__ void bin_pairs3(const int* __restrict__ s0, const int* __restrict__ d0, int E0,
                           const int* __restrict__ s1, const int* __restrict__ d1, int E1,
                           const int* __restrict__ s2, const int* __restrict__ d2, int E2,
                           int nbV,
                           unsigned int* __restrict__ pairs, int* __restrict__ bincnt,
                           int* __restrict__ o0, int* __restrict__ o1, int* __restrict__ o2,
                           int* __restrict__ ovf_cnt) {
    long e = (long)blockIdx.x * blockDim.x + threadIdx.x;
    const int* src; const int* dst; int le; long binBase; int* ovf; int* oc;
    if (e < E0)                      { src = s0; dst = d0; le = (int)e;           binBase = 0;        ovf = o0; oc = ovf_cnt +  0; }
    else if (e < (long)E0 + E1)      { src = s1; dst = d1; le = (int)(e - E0);    binBase = nbV;      ovf = o1; oc = ovf_cnt + 16; }
    else if (e < (long)E0 + E1 + E2) { src = s2; dst = d2; le = (int)(e - E0 - E1); binBase = 2 * nbV; ovf = o2; oc = ovf_cnt + 32; }
    else return;
    int d = dst[le], s = src[le];
    long b = binBase + (d >> 8);
    int p = atomicAdd(&bincnt[b], 1);
    if (p < CAPB) pairs[b * CAPB + p] = ((unsigned int)s << 8) | (unsigned int)(d & 255);
    else          ovf[atomicAdd(oc, 1)] = le;          // exact fallback (never hit w/ uniform dsts)
}

// ---------------- pass 2: per-bin CSR build (LDS histogram + scan + scatter) ----------------
__launch_bounds__(256)
__global__ void build_csr(int nbV, int Nvar, int Ncon,
                          const unsigned int* __restrict__ pairs, const int* __restrict__ bincnt,
                          unsigned int* __restrict__ csr, unsigned int* __restrict__ rowinfo) {
    const int b = blockIdx.x;
    int N, dstBase, infoBase;
    if (b < nbV)          { N = Nvar; dstBase = b * 256;             infoBase = 0; }
    else if (b < 2 * nbV) { N = Nvar; dstBase = (b - nbV) * 256;     infoBase = Nvar; }
    else                  { N = Ncon; dstBase = (b - 2 * nbV) * 256; infoBase = 2 * Nvar; }

    int n = bincnt[b]; if (n > CAPB) n = CAPB;
    const long base = (long)b * CAPB;
    __shared__ int hist[256], scan[256], cur[256];
    const int t = threadIdx.x;
    hist[t] = 0;
    __syncthreads();
    for (int i = t; i < n; i += 256) atomicAdd(&hist[pairs[base + i] & 255], 1);
    __syncthreads();
    scan[t] = hist[t];
    __syncthreads();
    for (int off = 1; off < 256; off <<= 1) {
        int u = (t >= off) ? scan[t - off] : 0;
        __syncthreads();
        scan[t] += u;
        __syncthreads();
    }
    const int excl = scan[t] - hist[t];
    cur[t] = excl;
    if (dstBase + t < N)
        rowinfo[infoBase + dstBase + t] = ((unsigned int)excl << 16) | (unsigned int)hist[t];
    __syncthreads();
    for (int i = t; i < n; i += 256) {
        unsigned int pr = pairs[base + i];
        int slot = atomicAdd(&cur[pr & 255], 1);   // LDS atomic
        csr[base + slot] = pr >> 8;                 // src index
    }
}

// ---------------- pass 3: pull-aggregate from CSR (one wave per dst) ----------------
// Same gather engine as before (two 32-lane halves each gather a different edge row,
// unrolled x2 -> 4 rows in flight); indices now come from a CONTIGUOUS CSR slice.
__launch_bounds__(256)
__global__ void pull_csr3(int Nvar, int Ncon, int nbV,
                          const unsigned short* __restrict__ xv, const unsigned short* __restrict__ xr,
                          const unsigned int* __restrict__ csr, const unsigned int* __restrict__ rowinfo,
                          const int* __restrict__ bincnt,
                          const int* __restrict__ s0, const int* __restrict__ d0, const int* __restrict__ o0,
                          const int* __restrict__ s1, const int* __restrict__ d1, const int* __restrict__ o1,
                          const int* __restrict__ s2, const int* __restrict__ d2, const int* __restrict__ o2,
                          const int* __restrict__ ovf_cnt,
                          unsigned short* __restrict__ agg_adj, unsigned short* __restrict__ agg_g,
                          unsigned short* __restrict__ agg_t) {
    int gwid = (int)(((long)blockIdx.x * blockDim.x + threadIdx.x) >> 6);
    int lane = threadIdx.x & 63;

    const unsigned short* y; const int* src; const int* dst; const int* ovf; int oc;
    long binBase; int infoBase; int wid; unsigned short* agg;
    if (gwid < Nvar) {
        y = xv; src = s0; dst = d0; ovf = o0; oc = ovf_cnt[0];  binBase = 0;        infoBase = 0;        agg = agg_adj; wid = gwid;
    } else if (gwid < 2 * Nvar) {
        y = xr; src = s1; dst = d1; ovf = o1; oc = ovf_cnt[16]; binBase = nbV;      infoBase = Nvar;     agg = agg_g;   wid = gwid - Nvar;
    } else if (gwid < 2 * Nvar + Ncon) {
        y = xv; src = s2; dst = d2; ovf = o2; oc = ovf_cnt[32]; binBase = 2 * nbV;  infoBase = 2 * Nvar; agg = agg_t;   wid = gwid - 2 * Nvar;
    } else return;

    const int half = lane >> 5;          // 0: even edge of pair, 1: odd edge
    const int hl = lane & 31;            // column group: cols [hl*4 .. hl*4+3]
    const long colOff = (long)hl * 4;

    const unsigned int info = rowinfo[infoBase + wid];
    const int mc = (int)(info & 0xffffu);
    const long b = binBase + (wid >> 8);
    const long cbase = b * CAPB + (long)(info >> 16);

    float acc0 = 0.f, acc1 = 0.f, acc2 = 0.f, acc3 = 0.f;

    for (int cb = 0; cb < mc; cb += 64) {
        int rem = mc - cb; if (rem > 64) rem = 64;
        int idx = (lane < rem) ? (int)csr[cbase + cb + lane] : 0;
        for (int j = 0; j < rem; j += 4) {
            int e0 = j + half;
            int e1 = j + 2 + half;
            int v0 = __shfl(idx, e0, 64);    // slots < 64; inactive -> row 0 (valid addr)
            int v1 = __shfl(idx, e1, 64);
            uint2 r0 = *(const uint2*)(y + (long)v0 * D + colOff);
            uint2 r1 = *(const uint2*)(y + (long)v1 * D + colOff);
            if (e0 >= rem) { r0.x = 0u; r0.y = 0u; }   // branchless; bf16 0-bits == 0.0f
            if (e1 >= rem) { r1.x = 0u; r1.y = 0u; }
            acc0 += bf2f(r0.x & 0xffffu) + bf2f(r1.x & 0xffffu);
            acc1 += bf2f(r0.x >> 16)     + bf2f(r1.x >> 16);
            acc2 += bf2f(r0.y & 0xffffu) + bf2f(r1.y & 0xffffu);
            acc3 += bf2f(r0.y >> 16)     + bf2f(r1.y >> 16);
        }
    }

    if (bincnt[b] > CAPB) {              // rare: bin overflowed -> exact scan of ovf list
        for (int i = 0; i < oc; ++i) {
            int e = ovf[i];
            if (dst[e] == wid && half == 0) {
                int s = src[e];
                uint2 r = *(const uint2*)(y + (long)s * D + colOff);
                acc0 += bf2f(r.x & 0xffffu);
                acc1 += bf2f(r.x >> 16);
                acc2 += bf2f(r.y & 0xffffu);
                acc3 += bf2f(r.y >> 16);
            }
        }
    }

    // combine the two halves (lane <-> lane+32)
    acc0 += __shfl_xor(acc0, 32, 64);
    acc1 += __shfl_xor(acc1, 32, 64);
    acc2 += __shfl_xor(acc2, 32, 64);
    acc3 += __shfl_xor(acc3, 32, 64);

    if (half == 0) {
        uint2 o;
        o.x = (unsigned int)f2bf(acc0) | ((unsigned int)f2bf(acc1) << 16);
        o.y = (unsigned int)f2bf(acc2) | ((unsigned int)f2bf(acc3) << 16);
        *(uint2*)(agg + (long)wid * D + colOff) = o;
    }
}

// ---------------- fused MFMA GEMM, LDS-staged (m97-style 2-phase) — R2-verbatim ----------------
__launch_bounds__(256, 4)
__global__ void gemm_fused(int N,
                           const unsigned short* __restrict__ A0, const unsigned short* __restrict__ Wt0,
                           const unsigned short* __restrict__ A1, const unsigned short* __restrict__ Wt1,
                           const unsigned short* __restrict__ A2, const unsigned short* __restrict__ Wt2,
                           int nTerms,
                           const float* __restrict__ bias, float* __restrict__ out,
                           float* __restrict__ gsum, float* __restrict__ gsq) {
    __shared__ unsigned short lds[2][8192];   // per buf: A slots 0..511 (8KB), B slots at +4096 (8KB)
    __shared__ float sstat[256];
    const int tx = threadIdx.x;
    sstat[tx] = 0.f;

    const int wave = tx >> 6, lane = tx & 63;
    const int quad = lane >> 4, l16 = lane & 15;
    const int row0 = blockIdx.x * 128;

    const int sA0 = tx, sA1 = tx + 256;
    const int rS0 = sA0 >> 2, qS0 = (sA0 & 3) ^ ((sA0 >> 4) & 3);
    const int rS1 = sA1 >> 2, qS1 = (sA1 & 3) ^ ((sA1 >> 4) & 3);
    long gr0 = (long)row0 + rS0; if (gr0 >= N) gr0 = N - 1;
    long gr1 = (long)row0 + rS1; if (gr1 >= N) gr1 = N - 1;

    f32x4 acc[2][8];
#pragma unroll
    for (int rt = 0; rt < 2; ++rt)
#pragma unroll
        for (int ct = 0; ct < 8; ++ct)
#pragma unroll
            for (int i = 0; i < 4; ++i) acc[rt][ct][i] = 0.f;

    auto stage = [&](int s, int bb) {
        const int t = s >> 2;
        const int k0 = (s & 3) * 32;
        const unsigned short* A = (t == 0) ? A0 : ((t == 1) ? A1 : A2);
        const unsigned short* W = (t == 0) ? Wt0 : ((t == 1) ? Wt1 : Wt2);
        __builtin_amdgcn_global_load_lds(
            (const __attribute__((address_space(1))) unsigned int*)(A + gr0 * D + k0 + qS0 * 8),
            (__attribute__((address_space(3))) unsigned int*)(&lds[bb][sA0 * 8]), 16, 0, 0);
        __builtin_amdgcn_global_load_lds(
            (const __attribute__((address_space(1))) unsigned int*)(A + gr1 * D + k0 + qS1 * 8),
            (__attribute__((address_space(3))) unsigned int*)(&lds[bb][sA1 * 8]), 16, 0, 0);
        __builtin_amdgcn_global_load_lds(
            (const __attribute__((address_space(1))) unsigned int*)(W + (long)rS0 * D + k0 + qS0 * 8),
            (__attribute__((address_space(3))) unsigned int*)(&lds[bb][4096 + sA0 * 8]), 16, 0, 0);
        __builtin_amdgcn_global_load_lds(
            (const __attribute__((address_space(1))) unsigned int*)(W + (long)rS1 * D + k0 + qS1 * 8),
            (__attribute__((address_space(3))) unsigned int*)(&lds[bb][4096 + sA1 * 8]), 16, 0, 0);
    };

    const int xq = (l16 >> 2) & 3;
    const int qx = quad ^ xq;

    auto compute = [&](int cb) {
        const int slotA0 = (wave * 32 + l16) * 4 + qx;
        const int slotA1 = (wave * 32 + 16 + l16) * 4 + qx;
        bf16x8 a0 = *(const bf16x8*)&lds[cb][slotA0 * 8];
        bf16x8 a1 = *(const bf16x8*)&lds[cb][slotA1 * 8];
#pragma unroll
        for (int ct = 0; ct < 8; ++ct) {
            const int slotB = (ct * 16 + l16) * 4 + qx;
            bf16x8 b = *(const bf16x8*)&lds[cb][4096 + slotB * 8];
            acc[0][ct] = __builtin_amdgcn_mfma_f32_16x16x32_bf16(a0, b, acc[0][ct], 0, 0, 0);
            acc[1][ct] = __builtin_amdgcn_mfma_f32_16x16x32_bf16(a1, b, acc[1][ct], 0, 0, 0);
        }
    };

    const int nsteps = nTerms * 4;
    stage(0, 0);
    __syncthreads();
    for (int s = 0; s < nsteps; ++s) {
        const int cb = s & 1;
        if (s + 1 < nsteps) stage(s + 1, cb ^ 1);
        compute(cb);
        __syncthreads();
    }

    float bv[8];
#pragma unroll
    for (int ct = 0; ct < 8; ++ct) bv[ct] = bias[ct * 16 + l16];

    float psum[8], psq[8];
#pragma unroll
    for (int ct = 0; ct < 8; ++ct) { psum[ct] = 0.f; psq[ct] = 0.f; }

#pragma unroll
    for (int rt = 0; rt < 2; ++rt)
#pragma unroll
        for (int i = 0; i < 4; ++i) {
            int row = row0 + wave * 32 + rt * 16 + quad * 4 + i;
            if (row < N) {
#pragma unroll
                for (int ct = 0; ct < 8; ++ct) {
                    float v = acc[rt][ct][i] + bv[ct];
                    out[(size_t)row * D + ct * 16 + l16] = v;
                    psum[ct] += v;
                    psq[ct] += v * v;
                }
            }
        }

#pragma unroll
    for (int ct = 0; ct < 8; ++ct) {
        atomicAdd(&sstat[ct * 16 + l16], psum[ct]);
        atomicAdd(&sstat[128 + ct * 16 + l16], psq[ct]);
    }
    __syncthreads();
    if (tx < 128) {
        atomAddF(&gsum[tx], sstat[tx]);
        atomAddF(&gsq[tx], sstat[128 + tx]);
    }
}

// ---------------- stats -> scale/shift ----------------
__global__ void finalize_stats(const float* __restrict__ stats,
                               const float* __restrict__ wv, const float* __restrict__ bv, const float* __restrict__ msv,
                               const float* __restrict__ wc, const float* __restrict__ bc, const float* __restrict__ msc,
                               int Nvar, int Ncon,
                               float* __restrict__ scale_var, float* __restrict__ shift_var,
                               float* __restrict__ scale_con, float* __restrict__ shift_con) {
    int tx = threadIdx.x;
    if (tx < 128) {
        float n = (float)Nvar;
        float mu = stats[tx] / n;
        float ex2 = stats[128 + tx] / n;
        float ms = msv[tx];
        float var = ex2 - 2.f * ms * mu * mu + ms * ms * mu * mu;
        float istd = rsqrtf(var + 1e-5f);
        float sc = wv[tx] * istd;
        scale_var[tx] = sc;
        shift_var[tx] = bv[tx] - sc * ms * mu;
    } else if (tx < 256) {
        int t = tx - 128;
        float n = (float)Ncon;
        float mu = stats[256 + t] / n;
        float ex2 = stats[384 + t] / n;
        float ms = msc[t];
        float var = ex2 - 2.f * ms * mu * mu + ms * ms * mu * mu;
        float istd = rsqrtf(var + 1e-5f);
        float sc = wc[t] * istd;
        scale_con[t] = sc;
        shift_con[t] = bc[t] - sc * ms * mu;
    }
}

// ---------------- fused in-place normalize + relu (var then con, contiguous) ----------------
__global__ void norm_relu2(float* __restrict__ buf,
                           long nvecVar, long nvecTot,
                           const float* __restrict__ sv, const float* __restrict__ hv,
                           const float* __restrict__ sc2, const float* __restrict__ hc) {
    long i = (long)blockIdx.x * blockDim.x + threadIdx.x;
    if (i >= nvecTot) return;
    const float* scale; const float* shift;
    if (i < nvecVar) { scale = sv; shift = hv; } else { scale = sc2; shift = hc; }
    int q = ((int)i & 31) * 4;
    float4 v = *(float4*)(buf + i * 4);
    float4 o;
    o.x = fmaxf(0.f, v.x * scale[q + 0] + shift[q + 0]);
    o.y = fmaxf(0.f, v.y * scale[q + 1] + shift[q + 1]);
    o.z = fmaxf(0.f, v.z * scale[q + 2] + shift[q + 2]);
    o.w = fmaxf(0.f, v.w * scale[q + 3] + shift[q + 3]);
    *(float4*)(buf + i * 4) = o;
}

extern "C" void kernel_launch(void* const* d_in, const int* in_sizes, int n_in,
                              void* d_out, int out_size, void* d_ws, size_t ws_size,
                              hipStream_t stream) {
    const float* x_var = (const float*)d_in[0];
    const float* x_con = (const float*)d_in[1];
    const float* x_reg = (const float*)d_in[2];
    const int* src_adj = (const int*)d_in[3];
    const int* dst_adj = (const int*)d_in[4];
    const int* src_t   = (const int*)d_in[5];
    const int* dst_t   = (const int*)d_in[6];
    const int* src_g   = (const int*)d_in[7];
    const int* dst_g   = (const int*)d_in[8];
    const float* W_rel_adj  = (const float*)d_in[9];
    const float* b_adj      = (const float*)d_in[10];
    const float* W_root_adj = (const float*)d_in[11];
    const float* W_rel_t    = (const float*)d_in[12];
    const float* b_t        = (const float*)d_in[13];
    const float* W_root_t   = (const float*)d_in[14];
    const float* W_rel_g    = (const float*)d_in[15];
    const float* b_g        = (const float*)d_in[16];
    const float* W_root_g   = (const float*)d_in[17];
    const float* gnw_v  = (const float*)d_in[18];
    const float* gnb_v  = (const float*)d_in[19];
    const float* gnms_v = (const float*)d_in[20];
    const float* gnw_c  = (const float*)d_in[21];
    const float* gnb_c  = (const float*)d_in[22];
    const float* gnms_c = (const float*)d_in[23];

    const int Nvar = in_sizes[0] / D;
    const int Ncon = in_sizes[1] / D;
    const int Nreg = in_sizes[2] / D;
    const int Eadj = in_sizes[3];
    const int Et   = in_sizes[5];
    const int Eg   = in_sizes[7];

    const int nbV = (Nvar + 255) >> 8;     // bins per var-dst graph (adj, groups)
    const int nbC = (Ncon + 255) >> 8;     // bins for touch
    const int totBins = 2 * nbV + nbC;

    // ---- workspace layout (large blocks first, all 256B-aligned) ----
    char* p = (char*)d_ws;
    unsigned short* xv_bf = (unsigned short*)p; p += (size_t)Nvar * D * 2;
    unsigned short* xc_bf = (unsigned short*)p; p += (size_t)Ncon * D * 2;
    unsigned short* xr_bf = (unsigned short*)p; p += (size_t)Nreg * D * 2;
    unsigned short* agg_adj = (unsigned short*)p; p += (size_t)Nvar * D * 2;
    unsigned short* agg_g   = (unsigned short*)p; p += (size_t)Nvar * D * 2;
    unsigned short* agg_t   = (unsigned short*)p; p += (size_t)Ncon * D * 2;
    unsigned int* pairs = (unsigned int*)p; p += (size_t)totBins * CAPB * 4;
    unsigned int* csr   = (unsigned int*)p; p += (size_t)totBins * CAPB * 4;
    unsigned int* rowinfo = (unsigned int*)p; p += (size_t)(2 * Nvar + Ncon) * 4;
    int* ovf0 = (int*)p; p += (size_t)Eadj * 4;
    int* ovf1 = (int*)p; p += (size_t)Eg * 4;
    int* ovf2 = (int*)p; p += (size_t)Et * 4;
    unsigned short* Wt_adj    = (unsigned short*)p; p += D * D * 2;
    unsigned short* Wt_g      = (unsigned short*)p; p += D * D * 2;
    unsigned short* Wt_t      = (unsigned short*)p; p += D * D * 2;
    unsigned short* Wt_root_t = (unsigned short*)p; p += D * D * 2;
    unsigned short* Wt_sum    = (unsigned short*)p; p += D * D * 2;
    float* bsum  = (float*)p; p += D * 4;
    float* scale_var = (float*)p; p += D * 4;
    float* shift_var = (float*)p; p += D * 4;
    float* scale_con = (float*)p; p += D * 4;
    float* shift_con = (float*)p; p += D * 4;
    // ---- contiguous zero region: stats(512f) + ovf_cnt(64i) + bincnt(totBins) ----
    char* zbase = p;
    float* stats   = (float*)p; p += 512 * 4;
    int* ovf_cnt   = (int*)p;   p += 64 * 4;         // [0],[16],[32] used
    int* bincnt    = (int*)p;   p += (size_t)totBins * 4;
    size_t zbytes = (size_t)(p - zbase);

    float* out_var = (float*)d_out;
    float* out_con = out_var + (size_t)Nvar * D;

    // 1: one memset covers stats + ovf counters + bin counters
    hipMemsetAsync(zbase, 0, zbytes, stream);

    // 2: weights
    prep_weights<<<64, 256, 0, stream>>>(W_rel_adj, W_rel_g, W_rel_t, W_root_t,
                                         W_root_adj, W_root_g, b_adj, b_g,
                                         Wt_adj, Wt_g, Wt_t, Wt_root_t, Wt_sum, bsum);

    // 3: fused casts
    {
        long n4v = (long)Nvar * 32, n4c = (long)Ncon * 32, n4r = (long)Nreg * 32;
        long tot = n4v + n4c + n4r;
        cast_bf16_3<<<(int)((tot + 255) / 256), 256, 0, stream>>>(
            x_var, n4v, x_con, n4c, x_reg, n4r, xv_bf, xc_bf, xr_bf);
    }

    // 4: bin pass (graph order: adj, groups, touch)
    {
        long Etot = (long)Eadj + Eg + Et;
        bin_pairs3<<<(int)((Etot + 255) / 256), 256, 0, stream>>>(
            src_adj, dst_adj, Eadj,
            src_g,   dst_g,   Eg,
            src_t,   dst_t,   Et,
            nbV, pairs, bincnt, ovf0, ovf1, ovf2, ovf_cnt);
    }

    // 5: per-bin CSR build
    build_csr<<<totBins, 256, 0, stream>>>(nbV, Nvar, Ncon, pairs, bincnt, csr, rowinfo);

    // 6: pull-aggregate from CSR
    {
        long T = ((long)2 * Nvar + Ncon) * 64;
        pull_csr3<<<(int)((T + 255) / 256), 256, 0, stream>>>(
            Nvar, Ncon, nbV, xv_bf, xr_bf,
            csr, rowinfo, bincnt,
            src_adj, dst_adj, ovf0,
            src_g,   dst_g,   ovf1,
            src_t,   dst_t,   ovf2,
            ovf_cnt, agg_adj, agg_g, agg_t);
    }

    // 7,8: GEMMs (R2-verbatim structure)
    gemm_fused<<<(Nvar + 127) / 128, 256, 0, stream>>>(Nvar,
        agg_adj, Wt_adj, agg_g, Wt_g, xv_bf, Wt_sum, 3,
        bsum, out_var, stats, stats + 128);
    gemm_fused<<<(Ncon + 127) / 128, 256, 0, stream>>>(Ncon,
        agg_t, Wt_t, xc_bf, Wt_root_t, nullptr, nullptr, 2,
        b_t, out_con, stats + 256, stats + 384);

    // 9: stats -> scale/shift
    finalize_stats<<<1, 256, 0, stream>>>(stats,
        gnw_v, gnb_v, gnms_v, gnw_c, gnb_c, gnms_c,
        Nvar, Ncon, scale_var, shift_var, scale_con, shift_con);

    // 10: fused normalize+relu over the contiguous [out_var | out_con] buffer
    {
        long nvecVar = (long)Nvar * 32;
        long nvecTot = (long)(Nvar + Ncon) * 32;
        norm_relu2<<<(int)((nvecTot + 255) / 256), 256, 0, stream>>>(
            out_var, nvecVar, nvecTot, scale_var, shift_var, scale_con, shift_con);
    }
}

// Round 7
// 761.378 us; speedup vs baseline: 1.4559x; 1.4559x over previous
//
#include <hip/hip_runtime.h>
#include <hip/hip_bf16.h>

#define D 128
#define CAPB 2048     // CSR capacity per 256-dst bin (mean ~1300; ovf fallback exact)
#define MAXBINS 4096  // LDS bin-counter capacity (harness: ~1955 bins)

typedef __attribute__((ext_vector_type(8))) short bf16x8;
typedef __attribute__((ext_vector_type(4))) float f32x4;

__device__ __forceinline__ void atomAddF(float* p, float v) { unsafeAtomicAdd(p, v); }

__device__ __forceinline__ unsigned short f2bf(float f) {
    __hip_bfloat16 h = __float2bfloat16(f);
    return *reinterpret_cast<unsigned short*>(&h);
}
__device__ __forceinline__ float bf2f(unsigned int u16) {
    unsigned int x = u16 << 16;
    return *reinterpret_cast<float*>(&x);
}

// ---------------- fused cast fp32 -> bf16 for all three node tensors ----------------
__global__ void cast_bf16_3(const float* __restrict__ a, long n4a,
                            const float* __restrict__ b, long n4b,
                            const float* __restrict__ c, long n4c,
                            unsigned short* __restrict__ oa,
                            unsigned short* __restrict__ ob,
                            unsigned short* __restrict__ oc) {
    long i = (long)blockIdx.x * blockDim.x + threadIdx.x;
    const float* in; unsigned short* out; long li;
    if (i < n4a)                { in = a; out = oa; li = i; }
    else if (i < n4a + n4b)     { in = b; out = ob; li = i - n4a; }
    else if (i < n4a + n4b + n4c) { in = c; out = oc; li = i - n4a - n4b; }
    else return;
    float4 v = ((const float4*)in)[li];
    ushort4 o;
    o.x = f2bf(v.x); o.y = f2bf(v.y); o.z = f2bf(v.z); o.w = f2bf(v.w);
    ((ushort4*)out)[li] = o;
}

// ---------------- weights: cast + transpose (Wt[n*128+k] = W[k*128+n]) ----------------
__global__ void prep_weights(const float* __restrict__ Wra, const float* __restrict__ Wrg,
                             const float* __restrict__ Wrt, const float* __restrict__ Wroot_t,
                             const float* __restrict__ Wroot_a, const float* __restrict__ Wroot_g,
                             const float* __restrict__ ba, const float* __restrict__ bg,
                             unsigned short* __restrict__ Wt_adj, unsigned short* __restrict__ Wt_g,
                             unsigned short* __restrict__ Wt_t, unsigned short* __restrict__ Wt_root_t,
                             unsigned short* __restrict__ Wt_sum, float* __restrict__ bsum) {
    int i = blockIdx.x * blockDim.x + threadIdx.x;
    if (i < D * D) {
        int k = i >> 7, n = i & 127;
        int ti = n * D + k;
        Wt_adj[ti]    = f2bf(Wra[i]);
        Wt_g[ti]      = f2bf(Wrg[i]);
        Wt_t[ti]      = f2bf(Wrt[i]);
        Wt_root_t[ti] = f2bf(Wroot_t[i]);
        Wt_sum[ti]    = f2bf(Wroot_a[i] + Wroot_g[i]);
    }
    if (i < D) bsum[i] = ba[i] + bg[i];
}

// ---------------- pass 1: LDS-aggregated binning (fixes R6's atomic contention) ----------------
// Each block owns a contiguous edge chunk. (a) count per-bin in LDS; (b) ONE global
// fetch-add per (block,bin) reserves a range (~250k atomics @ <=128-way contention vs
// R6's 2M @ ~1000-way); (c) re-scan chunk, scatter via LDS cursors -> writes within a
// bin are block-sequential -> line-local -> write-combined streaming.
__launch_bounds__(256)
__global__ void binscatter3(const int* __restrict__ s0, const int* __restrict__ d0, int E0,
                            const int* __restrict__ s1, const int* __restrict__ d1, int E1,
                            const int* __restrict__ s2, const int* __restrict__ d2, int E2,
                            int nbV, int totBins,
                            unsigned int* __restrict__ pairs, int* __restrict__ gbincnt,
                            int* __restrict__ o0, int* __restrict__ o1, int* __restrict__ o2,
                            int* __restrict__ ovf_cnt) {
    __shared__ int lb[MAXBINS];
    const int t = threadIdx.x;
    const long Etot = (long)E0 + E1 + E2;
    const long chunk = (Etot + gridDim.x - 1) / gridDim.x;
    const long start = (long)blockIdx.x * chunk;
    long end = start + chunk; if (end > Etot) end = Etot;

    for (int b = t; b < totBins; b += 256) lb[b] = 0;
    __syncthreads();

    for (long e = start + t; e < end; e += 256) {
        int bidx;
        if (e < E0)                    bidx = (d0[e] >> 8);
        else if (e < (long)E0 + E1)    bidx = nbV + (d1[e - E0] >> 8);
        else                           bidx = 2 * nbV + (d2[e - E0 - E1] >> 8);
        atomicAdd(&lb[bidx], 1);                 // LDS atomic: cheap
    }
    __syncthreads();
    for (int b = t; b < totBins; b += 256) {
        int c = lb[b];
        lb[b] = (c > 0) ? atomicAdd(&gbincnt[b], c) : 0;   // reserve range; lb now = base
    }
    __syncthreads();
    for (long e = start + t; e < end; e += 256) {
        int s, d, le, bidx; int* ovf; int* oc;
        if (e < E0)                 { le = (int)e;             s = s0[le]; d = d0[le]; bidx = (d >> 8);           ovf = o0; oc = ovf_cnt +  0; }
        else if (e < (long)E0 + E1) { le = (int)(e - E0);      s = s1[le]; d = d1[le]; bidx = nbV + (d >> 8);     ovf = o1; oc = ovf_cnt + 16; }
        else                        { le = (int)(e - E0 - E1); s = s2[le]; d = d2[le]; bidx = 2 * nbV + (d >> 8); ovf = o2; oc = ovf_cnt + 32; }
        int slot = atomicAdd(&lb[bidx], 1);      // LDS cursor (base + local order)
        if (slot < CAPB) pairs[(long)bidx * CAPB + slot] = ((unsigned int)s << 8) | (unsigned int)(d & 255);
        else             ovf[atomicAdd(oc, 1)] = le;          // exact fallback (never hit w/ uniform dsts)
    }
}

// ---------------- pass 2: per-bin CSR build (LDS histogram + scan + scatter) ----------------
__launch_bounds__(256)
__global__ void build_csr(int nbV, int Nvar, int Ncon,
                          const unsigned int* __restrict__ pairs, const int* __restrict__ bincnt,
                          unsigned int* __restrict__ csr, unsigned int* __restrict__ rowinfo) {
    const int b = blockIdx.x;
    int N, dstBase, infoBase;
    if (b < nbV)          { N = Nvar; dstBase = b * 256;             infoBase = 0; }
    else if (b < 2 * nbV) { N = Nvar; dstBase = (b - nbV) * 256;     infoBase = Nvar; }
    else                  { N = Ncon; dstBase = (b - 2 * nbV) * 256; infoBase = 2 * Nvar; }

    int n = bincnt[b]; if (n > CAPB) n = CAPB;
    const long base = (long)b * CAPB;
    __shared__ int hist[256], scan[256], cur[256];
    const int t = threadIdx.x;
    hist[t] = 0;
    __syncthreads();
    for (int i = t; i < n; i += 256) atomicAdd(&hist[pairs[base + i] & 255], 1);
    __syncthreads();
    scan[t] = hist[t];
    __syncthreads();
    for (int off = 1; off < 256; off <<= 1) {
        int u = (t >= off) ? scan[t - off] : 0;
        __syncthreads();
        scan[t] += u;
        __syncthreads();
    }
    const int excl = scan[t] - hist[t];
    cur[t] = excl;
    if (dstBase + t < N)
        rowinfo[infoBase + dstBase + t] = ((unsigned int)excl << 16) | (unsigned int)hist[t];
    __syncthreads();
    for (int i = t; i < n; i += 256) {
        unsigned int pr = pairs[base + i];
        int slot = atomicAdd(&cur[pr & 255], 1);   // LDS atomic
        csr[base + slot] = pr >> 8;                 // src index
    }
}

// ---------------- pass 3: pull-aggregate from CSR (one wave per dst) ----------------
// Upgraded engine: four 16-lane quarters each gather a DIFFERENT edge's row slice
// (lane = uint4 = 8 cols), unrolled x2 -> 8 rows in flight/wave; half the load
// instructions and half the VALU unpack per edge vs the uint2 engine.
__launch_bounds__(256)
__global__ void pull_csr3(int Nvar, int Ncon, int nbV,
                          const unsigned short* __restrict__ xv, const unsigned short* __restrict__ xr,
                          const unsigned int* __restrict__ csr, const unsigned int* __restrict__ rowinfo,
                          const int* __restrict__ bincnt,
                          const int* __restrict__ s0, const int* __restrict__ d0, const int* __restrict__ o0,
                          const int* __restrict__ s1, const int* __restrict__ d1, const int* __restrict__ o1,
                          const int* __restrict__ s2, const int* __restrict__ d2, const int* __restrict__ o2,
                          const int* __restrict__ ovf_cnt,
                          unsigned short* __restrict__ agg_adj, unsigned short* __restrict__ agg_g,
                          unsigned short* __restrict__ agg_t) {
    int gwid = (int)(((long)blockIdx.x * blockDim.x + threadIdx.x) >> 6);
    int lane = threadIdx.x & 63;

    const unsigned short* y; const int* src; const int* dst; const int* ovf; int oc;
    long binBase; int infoBase; int wid; unsigned short* agg;
    if (gwid < Nvar) {
        y = xv; src = s0; dst = d0; ovf = o0; oc = ovf_cnt[0];  binBase = 0;        infoBase = 0;        agg = agg_adj; wid = gwid;
    } else if (gwid < 2 * Nvar) {
        y = xr; src = s1; dst = d1; ovf = o1; oc = ovf_cnt[16]; binBase = nbV;      infoBase = Nvar;     agg = agg_g;   wid = gwid - Nvar;
    } else if (gwid < 2 * Nvar + Ncon) {
        y = xv; src = s2; dst = d2; ovf = o2; oc = ovf_cnt[32]; binBase = 2 * nbV;  infoBase = 2 * Nvar; agg = agg_t;   wid = gwid - 2 * Nvar;
    } else return;

    const int q  = lane >> 4;            // quarter 0..3: edge-slot within group of 4
    const int ql = lane & 15;            // column group: cols [ql*8 .. ql*8+7]
    const long colOff = (long)ql * 8;

    const unsigned int info = rowinfo[infoBase + wid];
    const int mc = (int)(info & 0xffffu);
    const long b = binBase + (wid >> 8);
    const long cbase = b * CAPB + (long)(info >> 16);

    float a0 = 0.f, a1 = 0.f, a2 = 0.f, a3 = 0.f, a4 = 0.f, a5 = 0.f, a6 = 0.f, a7 = 0.f;

    for (int cb = 0; cb < mc; cb += 64) {
        int rem = mc - cb; if (rem > 64) rem = 64;
        int idx = (lane < rem) ? (int)csr[cbase + cb + lane] : 0;
        for (int j = 0; j < rem; j += 8) {
            int e0 = j + q;
            int e1 = j + 4 + q;
            int v0 = __shfl(idx, e0, 64);    // slots < 64; inactive -> row 0 (valid addr)
            int v1 = __shfl(idx, e1, 64);
            uint4 r0 = *(const uint4*)(y + (long)v0 * D + colOff);
            uint4 r1 = *(const uint4*)(y + (long)v1 * D + colOff);
            if (e0 >= rem) { r0.x = 0u; r0.y = 0u; r0.z = 0u; r0.w = 0u; }   // branchless; bf16 0 == 0.0f
            if (e1 >= rem) { r1.x = 0u; r1.y = 0u; r1.z = 0u; r1.w = 0u; }
            a0 += bf2f(r0.x & 0xffffu) + bf2f(r1.x & 0xffffu);
            a1 += bf2f(r0.x >> 16)     + bf2f(r1.x >> 16);
            a2 += bf2f(r0.y & 0xffffu) + bf2f(r1.y & 0xffffu);
            a3 += bf2f(r0.y >> 16)     + bf2f(r1.y >> 16);
            a4 += bf2f(r0.z & 0xffffu) + bf2f(r1.z & 0xffffu);
            a5 += bf2f(r0.z >> 16)     + bf2f(r1.z >> 16);
            a6 += bf2f(r0.w & 0xffffu) + bf2f(r1.w & 0xffffu);
            a7 += bf2f(r0.w >> 16)     + bf2f(r1.w >> 16);
        }
    }

    if (bincnt[b] > CAPB) {              // rare: bin overflowed -> exact scan of ovf list
        for (int i = 0; i < oc; ++i) {
            int e = ovf[i];
            if (dst[e] == wid && q == 0) {   // count once (quarters are summed below)
                int s = src[e];
                uint4 r = *(const uint4*)(y + (long)s * D + colOff);
                a0 += bf2f(r.x & 0xffffu); a1 += bf2f(r.x >> 16);
                a2 += bf2f(r.y & 0xffffu); a3 += bf2f(r.y >> 16);
                a4 += bf2f(r.z & 0xffffu); a5 += bf2f(r.z >> 16);
                a6 += bf2f(r.w & 0xffffu); a7 += bf2f(r.w >> 16);
            }
        }
    }

    // combine the four quarters (lane, lane+16, lane+32, lane+48)
    a0 += __shfl_xor(a0, 16, 64); a0 += __shfl_xor(a0, 32, 64);
    a1 += __shfl_xor(a1, 16, 64); a1 += __shfl_xor(a1, 32, 64);
    a2 += __shfl_xor(a2, 16, 64); a2 += __shfl_xor(a2, 32, 64);
    a3 += __shfl_xor(a3, 16, 64); a3 += __shfl_xor(a3, 32, 64);
    a4 += __shfl_xor(a4, 16, 64); a4 += __shfl_xor(a4, 32, 64);
    a5 += __shfl_xor(a5, 16, 64); a5 += __shfl_xor(a5, 32, 64);
    a6 += __shfl_xor(a6, 16, 64); a6 += __shfl_xor(a6, 32, 64);
    a7 += __shfl_xor(a7, 16, 64); a7 += __shfl_xor(a7, 32, 64);

    if (lane < 16) {
        uint4 o;
        o.x = (unsigned int)f2bf(a0) | ((unsigned int)f2bf(a1) << 16);
        o.y = (unsigned int)f2bf(a2) | ((unsigned int)f2bf(a3) << 16);
        o.z = (unsigned int)f2bf(a4) | ((unsigned int)f2bf(a5) << 16);
        o.w = (unsigned int)f2bf(a6) | ((unsigned int)f2bf(a7) << 16);
        *(uint4*)(agg + (long)wid * D + colOff) = o;
    }
}

// ---------------- fused MFMA GEMM, LDS-staged (m97-style 2-phase) — R2-verbatim ----------------
__launch_bounds__(256, 4)
__global__ void gemm_fused(int N,
                           const unsigned short* __restrict__ A0, const unsigned short* __restrict__ Wt0,
                           const unsigned short* __restrict__ A1, const unsigned short* __restrict__ Wt1,
                           const unsigned short* __restrict__ A2, const unsigned short* __restrict__ Wt2,
                           int nTerms,
                           const float* __restrict__ bias, float* __restrict__ out,
                           float* __restrict__ gsum, float* __restrict__ gsq) {
    __shared__ unsigned short lds[2][8192];   // per buf: A slots 0..511 (8KB), B slots at +4096 (8KB)
    __shared__ float sstat[256];
    const int tx = threadIdx.x;
    sstat[tx] = 0.f;

    const int wave = tx >> 6, lane = tx & 63;
    const int quad = lane >> 4, l16 = lane & 15;
    const int row0 = blockIdx.x * 128;

    const int sA0 = tx, sA1 = tx + 256;
    const int rS0 = sA0 >> 2, qS0 = (sA0 & 3) ^ ((sA0 >> 4) & 3);
    const int rS1 = sA1 >> 2, qS1 = (sA1 & 3) ^ ((sA1 >> 4) & 3);
    long gr0 = (long)row0 + rS0; if (gr0 >= N) gr0 = N - 1;
    long gr1 = (long)row0 + rS1; if (gr1 >= N) gr1 = N - 1;

    f32x4 acc[2][8];
#pragma unroll
    for (int rt = 0; rt < 2; ++rt)
#pragma unroll
        for (int ct = 0; ct < 8; ++ct)
#pragma unroll
            for (int i = 0; i < 4; ++i) acc[rt][ct][i] = 0.f;

    auto stage = [&](int s, int bb) {
        const int t = s >> 2;
        const int k0 = (s & 3) * 32;
        const unsigned short* A = (t == 0) ? A0 : ((t == 1) ? A1 : A2);
        const unsigned short* W = (t == 0) ? Wt0 : ((t == 1) ? Wt1 : Wt2);
        __builtin_amdgcn_global_load_lds(
            (const __attribute__((address_space(1))) unsigned int*)(A + gr0 * D + k0 + qS0 * 8),
            (__attribute__((address_space(3))) unsigned int*)(&lds[bb][sA0 * 8]), 16, 0, 0);
        __builtin_amdgcn_global_load_lds(
            (const __attribute__((address_space(1))) unsigned int*)(A + gr1 * D + k0 + qS1 * 8),
            (__attribute__((address_space(3))) unsigned int*)(&lds[bb][sA1 * 8]), 16, 0, 0);
        __builtin_amdgcn_global_load_lds(
            (const __attribute__((address_space(1))) unsigned int*)(W + (long)rS0 * D + k0 + qS0 * 8),
            (__attribute__((address_space(3))) unsigned int*)(&lds[bb][4096 + sA0 * 8]), 16, 0, 0);
        __builtin_amdgcn_global_load_lds(
            (const __attribute__((address_space(1))) unsigned int*)(W + (long)rS1 * D + k0 + qS1 * 8),
            (__attribute__((address_space(3))) unsigned int*)(&lds[bb][4096 + sA1 * 8]), 16, 0, 0);
    };

    const int xq = (l16 >> 2) & 3;
    const int qx = quad ^ xq;

    auto compute = [&](int cb) {
        const int slotA0 = (wave * 32 + l16) * 4 + qx;
        const int slotA1 = (wave * 32 + 16 + l16) * 4 + qx;
        bf16x8 a0 = *(const bf16x8*)&lds[cb][slotA0 * 8];
        bf16x8 a1 = *(const bf16x8*)&lds[cb][slotA1 * 8];
#pragma unroll
        for (int ct = 0; ct < 8; ++ct) {
            const int slotB = (ct * 16 + l16) * 4 + qx;
            bf16x8 b = *(const bf16x8*)&lds[cb][4096 + slotB * 8];
            acc[0][ct] = __builtin_amdgcn_mfma_f32_16x16x32_bf16(a0, b, acc[0][ct], 0, 0, 0);
            acc[1][ct] = __builtin_amdgcn_mfma_f32_16x16x32_bf16(a1, b, acc[1][ct], 0, 0, 0);
        }
    };

    const int nsteps = nTerms * 4;
    stage(0, 0);
    __syncthreads();
    for (int s = 0; s < nsteps; ++s) {
        const int cb = s & 1;
        if (s + 1 < nsteps) stage(s + 1, cb ^ 1);
        compute(cb);
        __syncthreads();
    }

    float bv[8];
#pragma unroll
    for (int ct = 0; ct < 8; ++ct) bv[ct] = bias[ct * 16 + l16];

    float psum[8], psq[8];
#pragma unroll
    for (int ct = 0; ct < 8; ++ct) { psum[ct] = 0.f; psq[ct] = 0.f; }

#pragma unroll
    for (int rt = 0; rt < 2; ++rt)
#pragma unroll
        for (int i = 0; i < 4; ++i) {
            int row = row0 + wave * 32 + rt * 16 + quad * 4 + i;
            if (row < N) {
#pragma unroll
                for (int ct = 0; ct < 8; ++ct) {
                    float v = acc[rt][ct][i] + bv[ct];
                    out[(size_t)row * D + ct * 16 + l16] = v;
                    psum[ct] += v;
                    psq[ct] += v * v;
                }
            }
        }

#pragma unroll
    for (int ct = 0; ct < 8; ++ct) {
        atomicAdd(&sstat[ct * 16 + l16], psum[ct]);
        atomicAdd(&sstat[128 + ct * 16 + l16], psq[ct]);
    }
    __syncthreads();
    if (tx < 128) {
        atomAddF(&gsum[tx], sstat[tx]);
        atomAddF(&gsq[tx], sstat[128 + tx]);
    }
}

// ---------------- stats -> scale/shift ----------------
__global__ void finalize_stats(const float* __restrict__ stats,
                               const float* __restrict__ wv, const float* __restrict__ bv, const float* __restrict__ msv,
                               const float* __restrict__ wc, const float* __restrict__ bc, const float* __restrict__ msc,
                               int Nvar, int Ncon,
                               float* __restrict__ scale_var, float* __restrict__ shift_var,
                               float* __restrict__ scale_con, float* __restrict__ shift_con) {
    int tx = threadIdx.x;
    if (tx < 128) {
        float n = (float)Nvar;
        float mu = stats[tx] / n;
        float ex2 = stats[128 + tx] / n;
        float ms = msv[tx];
        float var = ex2 - 2.f * ms * mu * mu + ms * ms * mu * mu;
        float istd = rsqrtf(var + 1e-5f);
        float sc = wv[tx] * istd;
        scale_var[tx] = sc;
        shift_var[tx] = bv[tx] - sc * ms * mu;
    } else if (tx < 256) {
        int t = tx - 128;
        float n = (float)Ncon;
        float mu = stats[256 + t] / n;
        float ex2 = stats[384 + t] / n;
        float ms = msc[t];
        float var = ex2 - 2.f * ms * mu * mu + ms * ms * mu * mu;
        float istd = rsqrtf(var + 1e-5f);
        float sc = wc[t] * istd;
        scale_con[t] = sc;
        shift_con[t] = bc[t] - sc * ms * mu;
    }
}

// ---------------- fused in-place normalize + relu (var then con, contiguous) ----------------
__global__ void norm_relu2(float* __restrict__ buf,
                           long nvecVar, long nvecTot,
                           const float* __restrict__ sv, const float* __restrict__ hv,
                           const float* __restrict__ sc2, const float* __restrict__ hc) {
    long i = (long)blockIdx.x * blockDim.x + threadIdx.x;
    if (i >= nvecTot) return;
    const float* scale; const float* shift;
    if (i < nvecVar) { scale = sv; shift = hv; } else { scale = sc2; shift = hc; }
    int q = ((int)i & 31) * 4;
    float4 v = *(float4*)(buf + i * 4);
    float4 o;
    o.x = fmaxf(0.f, v.x * scale[q + 0] + shift[q + 0]);
    o.y = fmaxf(0.f, v.y * scale[q + 1] + shift[q + 1]);
    o.z = fmaxf(0.f, v.z * scale[q + 2] + shift[q + 2]);
    o.w = fmaxf(0.f, v.w * scale[q + 3] + shift[q + 3]);
    *(float4*)(buf + i * 4) = o;
}

extern "C" void kernel_launch(void* const* d_in, const int* in_sizes, int n_in,
                              void* d_out, int out_size, void* d_ws, size_t ws_size,
                              hipStream_t stream) {
    const float* x_var = (const float*)d_in[0];
    const float* x_con = (const float*)d_in[1];
    const float* x_reg = (const float*)d_in[2];
    const int* src_adj = (const int*)d_in[3];
    const int* dst_adj = (const int*)d_in[4];
    const int* src_t   = (const int*)d_in[5];
    const int* dst_t   = (const int*)d_in[6];
    const int* src_g   = (const int*)d_in[7];
    const int* dst_g   = (const int*)d_in[8];
    const float* W_rel_adj  = (const float*)d_in[9];
    const float* b_adj      = (const float*)d_in[10];
    const float* W_root_adj = (const float*)d_in[11];
    const float* W_rel_t    = (const float*)d_in[12];
    const float* b_t        = (const float*)d_in[13];
    const float* W_root_t   = (const float*)d_in[14];
    const float* W_rel_g    = (const float*)d_in[15];
    const float* b_g        = (const float*)d_in[16];
    const float* W_root_g   = (const float*)d_in[17];
    const float* gnw_v  = (const float*)d_in[18];
    const float* gnb_v  = (const float*)d_in[19];
    const float* gnms_v = (const float*)d_in[20];
    const float* gnw_c  = (const float*)d_in[21];
    const float* gnb_c  = (const float*)d_in[22];
    const float* gnms_c = (const float*)d_in[23];

    const int Nvar = in_sizes[0] / D;
    const int Ncon = in_sizes[1] / D;
    const int Nreg = in_sizes[2] / D;
    const int Eadj = in_sizes[3];
    const int Et   = in_sizes[5];
    const int Eg   = in_sizes[7];

    const int nbV = (Nvar + 255) >> 8;     // bins per var-dst graph (adj, groups)
    const int nbC = (Ncon + 255) >> 8;     // bins for touch
    const int totBins = 2 * nbV + nbC;

    // ---- workspace layout (large blocks first, all 256B-aligned) ----
    char* p = (char*)d_ws;
    unsigned short* xv_bf = (unsigned short*)p; p += (size_t)Nvar * D * 2;
    unsigned short* xc_bf = (unsigned short*)p; p += (size_t)Ncon * D * 2;
    unsigned short* xr_bf = (unsigned short*)p; p += (size_t)Nreg * D * 2;
    unsigned short* agg_adj = (unsigned short*)p; p += (size_t)Nvar * D * 2;
    unsigned short* agg_g   = (unsigned short*)p; p += (size_t)Nvar * D * 2;
    unsigned short* agg_t   = (unsigned short*)p; p += (size_t)Ncon * D * 2;
    unsigned int* pairs = (unsigned int*)p; p += (size_t)totBins * CAPB * 4;
    unsigned int* csr   = (unsigned int*)p; p += (size_t)totBins * CAPB * 4;
    unsigned int* rowinfo = (unsigned int*)p; p += (size_t)(2 * Nvar + Ncon) * 4;
    int* ovf0 = (int*)p; p += (size_t)Eadj * 4;
    int* ovf1 = (int*)p; p += (size_t)Eg * 4;
    int* ovf2 = (int*)p; p += (size_t)Et * 4;
    unsigned short* Wt_adj    = (unsigned short*)p; p += D * D * 2;
    unsigned short* Wt_g      = (unsigned short*)p; p += D * D * 2;
    unsigned short* Wt_t      = (unsigned short*)p; p += D * D * 2;
    unsigned short* Wt_root_t = (unsigned short*)p; p += D * D * 2;
    unsigned short* Wt_sum    = (unsigned short*)p; p += D * D * 2;
    float* bsum  = (float*)p; p += D * 4;
    float* scale_var = (float*)p; p += D * 4;
    float* shift_var = (float*)p; p += D * 4;
    float* scale_con = (float*)p; p += D * 4;
    float* shift_con = (float*)p; p += D * 4;
    // ---- contiguous zero region: stats(512f) + ovf_cnt(64i) + bincnt(totBins) ----
    char* zbase = p;
    float* stats   = (float*)p; p += 512 * 4;
    int* ovf_cnt   = (int*)p;   p += 64 * 4;         // [0],[16],[32] used
    int* bincnt    = (int*)p;   p += (size_t)totBins * 4;
    size_t zbytes = (size_t)(p - zbase);

    float* out_var = (float*)d_out;
    float* out_con = out_var + (size_t)Nvar * D;

    // 1: one memset covers stats + ovf counters + bin counters
    hipMemsetAsync(zbase, 0, zbytes, stream);

    // 2: weights
    prep_weights<<<64, 256, 0, stream>>>(W_rel_adj, W_rel_g, W_rel_t, W_root_t,
                                         W_root_adj, W_root_g, b_adj, b_g,
                                         Wt_adj, Wt_g, Wt_t, Wt_root_t, Wt_sum, bsum);

    // 3: fused casts
    {
        long n4v = (long)Nvar * 32, n4c = (long)Ncon * 32, n4r = (long)Nreg * 32;
        long tot = n4v + n4c + n4r;
        cast_bf16_3<<<(int)((tot + 255) / 256), 256, 0, stream>>>(
            x_var, n4v, x_con, n4c, x_reg, n4r, xv_bf, xc_bf, xr_bf);
    }

    // 4: LDS-aggregated bin+scatter (graph order: adj, groups, touch)
    binscatter3<<<128, 256, 0, stream>>>(
        src_adj, dst_adj, Eadj,
        src_g,   dst_g,   Eg,
        src_t,   dst_t,   Et,
        nbV, totBins, pairs, bincnt, ovf0, ovf1, ovf2, ovf_cnt);

    // 5: per-bin CSR build
    build_csr<<<totBins, 256, 0, stream>>>(nbV, Nvar, Ncon, pairs, bincnt, csr, rowinfo);

    // 6: pull-aggregate from CSR
    {
        long T = ((long)2 * Nvar + Ncon) * 64;
        pull_csr3<<<(int)((T + 255) / 256), 256, 0, stream>>>(
            Nvar, Ncon, nbV, xv_bf, xr_bf,
            csr, rowinfo, bincnt,
            src_adj, dst_adj, ovf0,
            src_g,   dst_g,   ovf1,
            src_t,   dst_t,   ovf2,
            ovf_cnt, agg_adj, agg_g, agg_t);
    }

    // 7,8: GEMMs (R2-verbatim structure)
    gemm_fused<<<(Nvar + 127) / 128, 256, 0, stream>>>(Nvar,
        agg_adj, Wt_adj, agg_g, Wt_g, xv_bf, Wt_sum, 3,
        bsum, out_var, stats, stats + 128);
    gemm_fused<<<(Ncon + 127) / 128, 256, 0, stream>>>(Ncon,
        agg_t, Wt_t, xc_bf, Wt_root_t, nullptr, nullptr, 2,
        b_t, out_con, stats + 256, stats + 384);

    // 9: stats -> scale/shift
    finalize_stats<<<1, 256, 0, stream>>>(stats,
        gnw_v, gnb_v, gnms_v, gnw_c, gnb_c, gnms_c,
        Nvar, Ncon, scale_var, shift_var, scale_con, shift_con);

    // 10: fused normalize+relu over the contiguous [out_var | out_con] buffer
    {
        long nvecVar = (long)Nvar * 32;
        long nvecTot = (long)(Nvar + Ncon) * 32;
        norm_relu2<<<(int)((nvecTot + 255) / 256), 256, 0, stream>>>(
            out_var, nvecVar, nvecTot, scale_var, shift_var, scale_con, shift_con);
    }
}

// Round 8
// 754.694 us; speedup vs baseline: 1.4688x; 1.0089x over previous
//
#include <hip/hip_runtime.h>
#include <hip/hip_bf16.h>

#define D 128
#define CAPB 2048     // CSR capacity per 256-dst bin (mean ~1300; ovf fallback exact)
#define MAXBINS 4096  // LDS bin-counter capacity (harness: ~1955 bins)

typedef __attribute__((ext_vector_type(8))) short bf16x8;
typedef __attribute__((ext_vector_type(4))) float f32x4;

__device__ __forceinline__ void atomAddF(float* p, float v) { unsafeAtomicAdd(p, v); }

__device__ __forceinline__ unsigned short f2bf(float f) {
    __hip_bfloat16 h = __float2bfloat16(f);
    return *reinterpret_cast<unsigned short*>(&h);
}
__device__ __forceinline__ float bf2f(unsigned int u16) {
    unsigned int x = u16 << 16;
    return *reinterpret_cast<float*>(&x);
}
// acc += ab.lo_bf16 * w.lo_bf16 + ab.hi_bf16 * w.hi_bf16   (one VALU op for 2 values)
__device__ __forceinline__ void dot2bf(float& acc, unsigned int ab, unsigned int w) {
    asm("v_dot2_f32_bf16 %0, %1, %2, %0" : "+v"(acc) : "v"(ab), "v"(w));
}

// ---------------- fused: weights-prep + zero-region + cast fp32->bf16 (x3) ----------------
// global-id partition: [0,16384) weights; [16384,+zwords) zero; rest: 4-elem casts.
__global__ void prep_cast_zero(const float* __restrict__ Wra, const float* __restrict__ Wrg,
                               const float* __restrict__ Wrt, const float* __restrict__ Wroot_t,
                               const float* __restrict__ Wroot_a, const float* __restrict__ Wroot_g,
                               const float* __restrict__ ba, const float* __restrict__ bg,
                               unsigned short* __restrict__ Wt_adj, unsigned short* __restrict__ Wt_g,
                               unsigned short* __restrict__ Wt_t, unsigned short* __restrict__ Wt_root_t,
                               unsigned short* __restrict__ Wt_sum, float* __restrict__ bsum,
                               unsigned int* __restrict__ zbase, long zwords,
                               const float* __restrict__ xa, long n4a,
                               const float* __restrict__ xb, long n4b,
                               const float* __restrict__ xc, long n4c,
                               unsigned short* __restrict__ oa,
                               unsigned short* __restrict__ ob,
                               unsigned short* __restrict__ oc) {
    long gid = (long)blockIdx.x * blockDim.x + threadIdx.x;
    if (gid < D * D) {
        int i = (int)gid;
        int k = i >> 7, n = i & 127;
        int ti = n * D + k;
        Wt_adj[ti]    = f2bf(Wra[i]);
        Wt_g[ti]      = f2bf(Wrg[i]);
        Wt_t[ti]      = f2bf(Wrt[i]);
        Wt_root_t[ti] = f2bf(Wroot_t[i]);
        Wt_sum[ti]    = f2bf(Wroot_a[i] + Wroot_g[i]);
        if (i < D) bsum[i] = ba[i] + bg[i];
        return;
    }
    gid -= D * D;
    if (gid < zwords) { zbase[gid] = 0u; return; }
    gid -= zwords;
    const float* in; unsigned short* out; long li;
    if (gid < n4a)                 { in = xa; out = oa; li = gid; }
    else if (gid < n4a + n4b)      { in = xb; out = ob; li = gid - n4a; }
    else if (gid < n4a + n4b + n4c){ in = xc; out = oc; li = gid - n4a - n4b; }
    else return;
    float4 v = ((const float4*)in)[li];
    ushort4 o;
    o.x = f2bf(v.x); o.y = f2bf(v.y); o.z = f2bf(v.z); o.w = f2bf(v.w);
    ((ushort4*)out)[li] = o;
}

// ---------------- pass 1: LDS-aggregated binning ----------------
__launch_bounds__(256)
__global__ void binscatter3(const int* __restrict__ s0, const int* __restrict__ d0, int E0,
                            const int* __restrict__ s1, const int* __restrict__ d1, int E1,
                            const int* __restrict__ s2, const int* __restrict__ d2, int E2,
                            int nbV, int totBins,
                            unsigned int* __restrict__ pairs, int* __restrict__ gbincnt,
                            int* __restrict__ o0, int* __restrict__ o1, int* __restrict__ o2,
                            int* __restrict__ ovf_cnt) {
    __shared__ int lb[MAXBINS];
    const int t = threadIdx.x;
    const long Etot = (long)E0 + E1 + E2;
    const long chunk = (Etot + gridDim.x - 1) / gridDim.x;
    const long start = (long)blockIdx.x * chunk;
    long end = start + chunk; if (end > Etot) end = Etot;

    for (int b = t; b < totBins; b += 256) lb[b] = 0;
    __syncthreads();

    for (long e = start + t; e < end; e += 256) {
        int bidx;
        if (e < E0)                    bidx = (d0[e] >> 8);
        else if (e < (long)E0 + E1)    bidx = nbV + (d1[e - E0] >> 8);
        else                           bidx = 2 * nbV + (d2[e - E0 - E1] >> 8);
        atomicAdd(&lb[bidx], 1);                 // LDS atomic: cheap
    }
    __syncthreads();
    for (int b = t; b < totBins; b += 256) {
        int c = lb[b];
        lb[b] = (c > 0) ? atomicAdd(&gbincnt[b], c) : 0;   // reserve range; lb now = base
    }
    __syncthreads();
    for (long e = start + t; e < end; e += 256) {
        int s, d, le, bidx; int* ovf; int* oc;
        if (e < E0)                 { le = (int)e;             s = s0[le]; d = d0[le]; bidx = (d >> 8);           ovf = o0; oc = ovf_cnt +  0; }
        else if (e < (long)E0 + E1) { le = (int)(e - E0);      s = s1[le]; d = d1[le]; bidx = nbV + (d >> 8);     ovf = o1; oc = ovf_cnt + 16; }
        else                        { le = (int)(e - E0 - E1); s = s2[le]; d = d2[le]; bidx = 2 * nbV + (d >> 8); ovf = o2; oc = ovf_cnt + 32; }
        int slot = atomicAdd(&lb[bidx], 1);      // LDS cursor (base + local order)
        if (slot < CAPB) pairs[(long)bidx * CAPB + slot] = ((unsigned int)s << 8) | (unsigned int)(d & 255);
        else             ovf[atomicAdd(oc, 1)] = le;          // exact fallback (never hit w/ uniform dsts)
    }
}

// ---------------- pass 2: per-bin CSR build (LDS histogram + scan + scatter) ----------------
__launch_bounds__(256)
__global__ void build_csr(int nbV, int Nvar, int Ncon,
                          const unsigned int* __restrict__ pairs, const int* __restrict__ bincnt,
                          unsigned int* __restrict__ csr, unsigned int* __restrict__ rowinfo) {
    const int b = blockIdx.x;
    int N, dstBase, infoBase;
    if (b < nbV)          { N = Nvar; dstBase = b * 256;             infoBase = 0; }
    else if (b < 2 * nbV) { N = Nvar; dstBase = (b - nbV) * 256;     infoBase = Nvar; }
    else                  { N = Ncon; dstBase = (b - 2 * nbV) * 256; infoBase = 2 * Nvar; }

    int n = bincnt[b]; if (n > CAPB) n = CAPB;
    const long base = (long)b * CAPB;
    __shared__ int hist[256], scan[256], cur[256];
    const int t = threadIdx.x;
    hist[t] = 0;
    __syncthreads();
    for (int i = t; i < n; i += 256) atomicAdd(&hist[pairs[base + i] & 255], 1);
    __syncthreads();
    scan[t] = hist[t];
    __syncthreads();
    for (int off = 1; off < 256; off <<= 1) {
        int u = (t >= off) ? scan[t - off] : 0;
        __syncthreads();
        scan[t] += u;
        __syncthreads();
    }
    const int excl = scan[t] - hist[t];
    cur[t] = excl;
    if (dstBase + t < N)
        rowinfo[infoBase + dstBase + t] = ((unsigned int)excl << 16) | (unsigned int)hist[t];
    __syncthreads();
    for (int i = t; i < n; i += 256) {
        unsigned int pr = pairs[base + i];
        int slot = atomicAdd(&cur[pr & 255], 1);   // LDS atomic
        csr[base + slot] = pr >> 8;                 // src index
    }
}

// ---------------- pass 3: pull-aggregate from CSR (one wave per dst) ----------------
// VALU-optimized engine: four 16-lane quarters each gather a different edge's row slice
// (lane = uint4 = 8 cols), 8 rows in flight/wave. Accumulate via v_perm_b32 (pack the
// SAME column of two edges into one dword) + v_dot2_f32_bf16 with a per-edge validity
// weight (1.0|1.0 bf16; zeroed half for inactive slots) -> 2 values/VALU-op vs 2 ops/value.
__launch_bounds__(256)
__global__ void pull_csr3(int Nvar, int Ncon, int nbV,
                          const unsigned short* __restrict__ xv, const unsigned short* __restrict__ xr,
                          const unsigned int* __restrict__ csr, const unsigned int* __restrict__ rowinfo,
                          const int* __restrict__ bincnt,
                          const int* __restrict__ s0, const int* __restrict__ d0, const int* __restrict__ o0,
                          const int* __restrict__ s1, const int* __restrict__ d1, const int* __restrict__ o1,
                          const int* __restrict__ s2, const int* __restrict__ d2, const int* __restrict__ o2,
                          const int* __restrict__ ovf_cnt,
                          unsigned short* __restrict__ agg_adj, unsigned short* __restrict__ agg_g,
                          unsigned short* __restrict__ agg_t) {
    int gwid = (int)(((long)blockIdx.x * blockDim.x + threadIdx.x) >> 6);
    int lane = threadIdx.x & 63;

    const unsigned short* y; const int* src; const int* dst; const int* ovf; int oc;
    long binBase; int infoBase; int wid; unsigned short* agg;
    if (gwid < Nvar) {
        y = xv; src = s0; dst = d0; ovf = o0; oc = ovf_cnt[0];  binBase = 0;        infoBase = 0;        agg = agg_adj; wid = gwid;
    } else if (gwid < 2 * Nvar) {
        y = xr; src = s1; dst = d1; ovf = o1; oc = ovf_cnt[16]; binBase = nbV;      infoBase = Nvar;     agg = agg_g;   wid = gwid - Nvar;
    } else if (gwid < 2 * Nvar + Ncon) {
        y = xv; src = s2; dst = d2; ovf = o2; oc = ovf_cnt[32]; binBase = 2 * nbV;  infoBase = 2 * Nvar; agg = agg_t;   wid = gwid - 2 * Nvar;
    } else return;

    const int q  = lane >> 4;            // quarter 0..3: edge-slot within group of 4
    const int ql = lane & 15;            // column group: cols [ql*8 .. ql*8+7]
    const long colOff = (long)ql * 8;

    const unsigned int info = rowinfo[infoBase + wid];
    const int mc = (int)(info & 0xffffu);
    const long b = binBase + (wid >> 8);
    const long cbase = b * CAPB + (long)(info >> 16);

    float a0 = 0.f, a1 = 0.f, a2 = 0.f, a3 = 0.f, a4 = 0.f, a5 = 0.f, a6 = 0.f, a7 = 0.f;

    for (int cb = 0; cb < mc; cb += 64) {
        int rem = mc - cb; if (rem > 64) rem = 64;
        int idx = (lane < rem) ? (int)csr[cbase + cb + lane] : 0;
        for (int j = 0; j < rem; j += 8) {
            int e0 = j + q;
            int e1 = j + 4 + q;
            int v0 = __shfl(idx, e0, 64);    // slots < 64; inactive -> row 0 (valid addr, weight 0)
            int v1 = __shfl(idx, e1, 64);
            uint4 r0 = *(const uint4*)(y + (long)v0 * D + colOff);
            uint4 r1 = *(const uint4*)(y + (long)v1 * D + colOff);
            unsigned int w = (e0 < rem ? 0x3F80u : 0u) | (e1 < rem ? 0x3F800000u : 0u);
            unsigned int p;
            // perm sel 0x01000504: dst = (r0.low_bf16, r1.low_bf16); 0x03020706: high halves
            p = __builtin_amdgcn_perm(r0.x, r1.x, 0x01000504u); dot2bf(a0, p, w);
            p = __builtin_amdgcn_perm(r0.x, r1.x, 0x03020706u); dot2bf(a1, p, w);
            p = __builtin_amdgcn_perm(r0.y, r1.y, 0x01000504u); dot2bf(a2, p, w);
            p = __builtin_amdgcn_perm(r0.y, r1.y, 0x03020706u); dot2bf(a3, p, w);
            p = __builtin_amdgcn_perm(r0.z, r1.z, 0x01000504u); dot2bf(a4, p, w);
            p = __builtin_amdgcn_perm(r0.z, r1.z, 0x03020706u); dot2bf(a5, p, w);
            p = __builtin_amdgcn_perm(r0.w, r1.w, 0x01000504u); dot2bf(a6, p, w);
            p = __builtin_amdgcn_perm(r0.w, r1.w, 0x03020706u); dot2bf(a7, p, w);
        }
    }

    if (bincnt[b] > CAPB) {              // rare: bin overflowed -> exact scan of ovf list
        for (int i = 0; i < oc; ++i) {
            int e = ovf[i];
            if (dst[e] == wid && q == 0) {   // count once (quarters are summed below)
                int s = src[e];
                uint4 r = *(const uint4*)(y + (long)s * D + colOff);
                a0 += bf2f(r.x & 0xffffu); a1 += bf2f(r.x >> 16);
                a2 += bf2f(r.y & 0xffffu); a3 += bf2f(r.y >> 16);
                a4 += bf2f(r.z & 0xffffu); a5 += bf2f(r.z >> 16);
                a6 += bf2f(r.w & 0xffffu); a7 += bf2f(r.w >> 16);
            }
        }
    }

    // combine the four quarters (lane, lane+16, lane+32, lane+48)
    a0 += __shfl_xor(a0, 16, 64); a0 += __shfl_xor(a0, 32, 64);
    a1 += __shfl_xor(a1, 16, 64); a1 += __shfl_xor(a1, 32, 64);
    a2 += __shfl_xor(a2, 16, 64); a2 += __shfl_xor(a2, 32, 64);
    a3 += __shfl_xor(a3, 16, 64); a3 += __shfl_xor(a3, 32, 64);
    a4 += __shfl_xor(a4, 16, 64); a4 += __shfl_xor(a4, 32, 64);
    a5 += __shfl_xor(a5, 16, 64); a5 += __shfl_xor(a5, 32, 64);
    a6 += __shfl_xor(a6, 16, 64); a6 += __shfl_xor(a6, 32, 64);
    a7 += __shfl_xor(a7, 16, 64); a7 += __shfl_xor(a7, 32, 64);

    if (lane < 16) {
        uint4 o;
        o.x = (unsigned int)f2bf(a0) | ((unsigned int)f2bf(a1) << 16);
        o.y = (unsigned int)f2bf(a2) | ((unsigned int)f2bf(a3) << 16);
        o.z = (unsigned int)f2bf(a4) | ((unsigned int)f2bf(a5) << 16);
        o.w = (unsigned int)f2bf(a6) | ((unsigned int)f2bf(a7) << 16);
        *(uint4*)(agg + (long)wid * D + colOff) = o;
    }
}

// ---------------- fused MFMA GEMM, LDS-staged (m97-style 2-phase) — R2-verbatim ----------------
__launch_bounds__(256, 4)
__global__ void gemm_fused(int N,
                           const unsigned short* __restrict__ A0, const unsigned short* __restrict__ Wt0,
                           const unsigned short* __restrict__ A1, const unsigned short* __restrict__ Wt1,
                           const unsigned short* __restrict__ A2, const unsigned short* __restrict__ Wt2,
                           int nTerms,
                           const float* __restrict__ bias, float* __restrict__ out,
                           float* __restrict__ gsum, float* __restrict__ gsq) {
    __shared__ unsigned short lds[2][8192];   // per buf: A slots 0..511 (8KB), B slots at +4096 (8KB)
    __shared__ float sstat[256];
    const int tx = threadIdx.x;
    sstat[tx] = 0.f;

    const int wave = tx >> 6, lane = tx & 63;
    const int quad = lane >> 4, l16 = lane & 15;
    const int row0 = blockIdx.x * 128;

    const int sA0 = tx, sA1 = tx + 256;
    const int rS0 = sA0 >> 2, qS0 = (sA0 & 3) ^ ((sA0 >> 4) & 3);
    const int rS1 = sA1 >> 2, qS1 = (sA1 & 3) ^ ((sA1 >> 4) & 3);
    long gr0 = (long)row0 + rS0; if (gr0 >= N) gr0 = N - 1;
    long gr1 = (long)row0 + rS1; if (gr1 >= N) gr1 = N - 1;

    f32x4 acc[2][8];
#pragma unroll
    for (int rt = 0; rt < 2; ++rt)
#pragma unroll
        for (int ct = 0; ct < 8; ++ct)
#pragma unroll
            for (int i = 0; i < 4; ++i) acc[rt][ct][i] = 0.f;

    auto stage = [&](int s, int bb) {
        const int t = s >> 2;
        const int k0 = (s & 3) * 32;
        const unsigned short* A = (t == 0) ? A0 : ((t == 1) ? A1 : A2);
        const unsigned short* W = (t == 0) ? Wt0 : ((t == 1) ? Wt1 : Wt2);
        __builtin_amdgcn_global_load_lds(
            (const __attribute__((address_space(1))) unsigned int*)(A + gr0 * D + k0 + qS0 * 8),
            (__attribute__((address_space(3))) unsigned int*)(&lds[bb][sA0 * 8]), 16, 0, 0);
        __builtin_amdgcn_global_load_lds(
            (const __attribute__((address_space(1))) unsigned int*)(A + gr1 * D + k0 + qS1 * 8),
            (__attribute__((address_space(3))) unsigned int*)(&lds[bb][sA1 * 8]), 16, 0, 0);
        __builtin_amdgcn_global_load_lds(
            (const __attribute__((address_space(1))) unsigned int*)(W + (long)rS0 * D + k0 + qS0 * 8),
            (__attribute__((address_space(3))) unsigned int*)(&lds[bb][4096 + sA0 * 8]), 16, 0, 0);
        __builtin_amdgcn_global_load_lds(
            (const __attribute__((address_space(1))) unsigned int*)(W + (long)rS1 * D + k0 + qS1 * 8),
            (__attribute__((address_space(3))) unsigned int*)(&lds[bb][4096 + sA1 * 8]), 16, 0, 0);
    };

    const int xq = (l16 >> 2) & 3;
    const int qx = quad ^ xq;

    auto compute = [&](int cb) {
        const int slotA0 = (wave * 32 + l16) * 4 + qx;
        const int slotA1 = (wave * 32 + 16 + l16) * 4 + qx;
        bf16x8 a0 = *(const bf16x8*)&lds[cb][slotA0 * 8];
        bf16x8 a1 = *(const bf16x8*)&lds[cb][slotA1 * 8];
#pragma unroll
        for (int ct = 0; ct < 8; ++ct) {
            const int slotB = (ct * 16 + l16) * 4 + qx;
            bf16x8 b = *(const bf16x8*)&lds[cb][4096 + slotB * 8];
            acc[0][ct] = __builtin_amdgcn_mfma_f32_16x16x32_bf16(a0, b, acc[0][ct], 0, 0, 0);
            acc[1][ct] = __builtin_amdgcn_mfma_f32_16x16x32_bf16(a1, b, acc[1][ct], 0, 0, 0);
        }
    };

    const int nsteps = nTerms * 4;
    stage(0, 0);
    __syncthreads();
    for (int s = 0; s < nsteps; ++s) {
        const int cb = s & 1;
        if (s + 1 < nsteps) stage(s + 1, cb ^ 1);
        compute(cb);
        __syncthreads();
    }

    float bv[8];
#pragma unroll
    for (int ct = 0; ct < 8; ++ct) bv[ct] = bias[ct * 16 + l16];

    float psum[8], psq[8];
#pragma unroll
    for (int ct = 0; ct < 8; ++ct) { psum[ct] = 0.f; psq[ct] = 0.f; }

#pragma unroll
    for (int rt = 0; rt < 2; ++rt)
#pragma unroll
        for (int i = 0; i < 4; ++i) {
            int row = row0 + wave * 32 + rt * 16 + quad * 4 + i;
            if (row < N) {
#pragma unroll
                for (int ct = 0; ct < 8; ++ct) {
                    float v = acc[rt][ct][i] + bv[ct];
                    out[(size_t)row * D + ct * 16 + l16] = v;
                    psum[ct] += v;
                    psq[ct] += v * v;
                }
            }
        }

#pragma unroll
    for (int ct = 0; ct < 8; ++ct) {
        atomicAdd(&sstat[ct * 16 + l16], psum[ct]);
        atomicAdd(&sstat[128 + ct * 16 + l16], psq[ct]);
    }
    __syncthreads();
    if (tx < 128) {
        atomAddF(&gsum[tx], sstat[tx]);
        atomAddF(&gsq[tx], sstat[128 + tx]);
    }
}

// ---------------- fused normalize+relu with per-block stats finalization ----------------
// Each block recomputes the 256 scale/shift values from stats into LDS (~2us total
// redundancy across the grid) -- removes the separate finalize_stats launch (~20us gap).
__global__ void norm_relu_fin(float* __restrict__ buf,
                              long nvecVar, long nvecTot,
                              const float* __restrict__ stats,
                              const float* __restrict__ wv, const float* __restrict__ bv, const float* __restrict__ msv,
                              const float* __restrict__ wc, const float* __restrict__ bc, const float* __restrict__ msc,
                              int Nvar, int Ncon) {
    __shared__ float ss[512];   // [0:128) scale_var [128:256) shift_var [256:384) scale_con [384:512) shift_con
    const int t = threadIdx.x;
    {
        const int col = t & 127;
        const bool isv = t < 128;
        const float n = isv ? (float)Nvar : (float)Ncon;
        const float* st = stats + (isv ? 0 : 256);
        const float mu = st[col] / n;
        const float ex2 = st[128 + col] / n;
        const float ms = (isv ? msv : msc)[col];
        const float var = ex2 - 2.f * ms * mu * mu + ms * ms * mu * mu;
        const float istd = rsqrtf(var + 1e-5f);
        const float sc = (isv ? wv : wc)[col] * istd;
        ss[(isv ? 0 : 256) + col] = sc;
        ss[(isv ? 128 : 384) + col] = (isv ? bv : bc)[col] - sc * ms * mu;
    }
    __syncthreads();
    long i = (long)blockIdx.x * blockDim.x + t;
    if (i >= nvecTot) return;
    const int base = (i < nvecVar) ? 0 : 256;
    const int q = ((int)i & 31) * 4;
    float4 v = *(float4*)(buf + i * 4);
    float4 o;
    o.x = fmaxf(0.f, v.x * ss[base + q + 0] + ss[base + 128 + q + 0]);
    o.y = fmaxf(0.f, v.y * ss[base + q + 1] + ss[base + 128 + q + 1]);
    o.z = fmaxf(0.f, v.z * ss[base + q + 2] + ss[base + 128 + q + 2]);
    o.w = fmaxf(0.f, v.w * ss[base + q + 3] + ss[base + 128 + q + 3]);
    *(float4*)(buf + i * 4) = o;
}

extern "C" void kernel_launch(void* const* d_in, const int* in_sizes, int n_in,
                              void* d_out, int out_size, void* d_ws, size_t ws_size,
                              hipStream_t stream) {
    const float* x_var = (const float*)d_in[0];
    const float* x_con = (const float*)d_in[1];
    const float* x_reg = (const float*)d_in[2];
    const int* src_adj = (const int*)d_in[3];
    const int* dst_adj = (const int*)d_in[4];
    const int* src_t   = (const int*)d_in[5];
    const int* dst_t   = (const int*)d_in[6];
    const int* src_g   = (const int*)d_in[7];
    const int* dst_g   = (const int*)d_in[8];
    const float* W_rel_adj  = (const float*)d_in[9];
    const float* b_adj      = (const float*)d_in[10];
    const float* W_root_adj = (const float*)d_in[11];
    const float* W_rel_t    = (const float*)d_in[12];
    const float* b_t        = (const float*)d_in[13];
    const float* W_root_t   = (const float*)d_in[14];
    const float* W_rel_g    = (const float*)d_in[15];
    const float* b_g        = (const float*)d_in[16];
    const float* W_root_g   = (const float*)d_in[17];
    const float* gnw_v  = (const float*)d_in[18];
    const float* gnb_v  = (const float*)d_in[19];
    const float* gnms_v = (const float*)d_in[20];
    const float* gnw_c  = (const float*)d_in[21];
    const float* gnb_c  = (const float*)d_in[22];
    const float* gnms_c = (const float*)d_in[23];

    const int Nvar = in_sizes[0] / D;
    const int Ncon = in_sizes[1] / D;
    const int Nreg = in_sizes[2] / D;
    const int Eadj = in_sizes[3];
    const int Et   = in_sizes[5];
    const int Eg   = in_sizes[7];

    const int nbV = (Nvar + 255) >> 8;     // bins per var-dst graph (adj, groups)
    const int nbC = (Ncon + 255) >> 8;     // bins for touch
    const int totBins = 2 * nbV + nbC;

    // ---- workspace layout (large blocks first, all 256B-aligned) ----
    char* p = (char*)d_ws;
    unsigned short* xv_bf = (unsigned short*)p; p += (size_t)Nvar * D * 2;
    unsigned short* xc_bf = (unsigned short*)p; p += (size_t)Ncon * D * 2;
    unsigned short* xr_bf = (unsigned short*)p; p += (size_t)Nreg * D * 2;
    unsigned short* agg_adj = (unsigned short*)p; p += (size_t)Nvar * D * 2;
    unsigned short* agg_g   = (unsigned short*)p; p += (size_t)Nvar * D * 2;
    unsigned short* agg_t   = (unsigned short*)p; p += (size_t)Ncon * D * 2;
    unsigned int* pairs = (unsigned int*)p; p += (size_t)totBins * CAPB * 4;
    unsigned int* csr   = (unsigned int*)p; p += (size_t)totBins * CAPB * 4;
    unsigned int* rowinfo = (unsigned int*)p; p += (size_t)(2 * Nvar + Ncon) * 4;
    int* ovf0 = (int*)p; p += (size_t)Eadj * 4;
    int* ovf1 = (int*)p; p += (size_t)Eg * 4;
    int* ovf2 = (int*)p; p += (size_t)Et * 4;
    unsigned short* Wt_adj    = (unsigned short*)p; p += D * D * 2;
    unsigned short* Wt_g      = (unsigned short*)p; p += D * D * 2;
    unsigned short* Wt_t      = (unsigned short*)p; p += D * D * 2;
    unsigned short* Wt_root_t = (unsigned short*)p; p += D * D * 2;
    unsigned short* Wt_sum    = (unsigned short*)p; p += D * D * 2;
    float* bsum  = (float*)p; p += D * 4;
    // ---- contiguous zero region: stats(512f) + ovf_cnt(64i) + bincnt(totBins) ----
    char* zbase = p;
    float* stats   = (float*)p; p += 512 * 4;
    int* ovf_cnt   = (int*)p;   p += 64 * 4;         // [0],[16],[32] used
    int* bincnt    = (int*)p;   p += (size_t)totBins * 4;
    const long zwords = (long)(p - zbase) / 4;

    float* out_var = (float*)d_out;
    float* out_con = out_var + (size_t)Nvar * D;

    // 1: fused weights-prep + zero + casts
    {
        long n4v = (long)Nvar * 32, n4c = (long)Ncon * 32, n4r = (long)Nreg * 32;
        long tot = (long)D * D + zwords + n4v + n4c + n4r;
        prep_cast_zero<<<(int)((tot + 255) / 256), 256, 0, stream>>>(
            W_rel_adj, W_rel_g, W_rel_t, W_root_t, W_root_adj, W_root_g, b_adj, b_g,
            Wt_adj, Wt_g, Wt_t, Wt_root_t, Wt_sum, bsum,
            (unsigned int*)zbase, zwords,
            x_var, n4v, x_con, n4c, x_reg, n4r, xv_bf, xc_bf, xr_bf);
    }

    // 2: LDS-aggregated bin+scatter (graph order: adj, groups, touch)
    binscatter3<<<128, 256, 0, stream>>>(
        src_adj, dst_adj, Eadj,
        src_g,   dst_g,   Eg,
        src_t,   dst_t,   Et,
        nbV, totBins, pairs, bincnt, ovf0, ovf1, ovf2, ovf_cnt);

    // 3: per-bin CSR build
    build_csr<<<totBins, 256, 0, stream>>>(nbV, Nvar, Ncon, pairs, bincnt, csr, rowinfo);

    // 4: pull-aggregate from CSR
    {
        long T = ((long)2 * Nvar + Ncon) * 64;
        pull_csr3<<<(int)((T + 255) / 256), 256, 0, stream>>>(
            Nvar, Ncon, nbV, xv_bf, xr_bf,
            csr, rowinfo, bincnt,
            src_adj, dst_adj, ovf0,
            src_g,   dst_g,   ovf1,
            src_t,   dst_t,   ovf2,
            ovf_cnt, agg_adj, agg_g, agg_t);
    }

    // 5,6: GEMMs (R2-verbatim structure)
    gemm_fused<<<(Nvar + 127) / 128, 256, 0, stream>>>(Nvar,
        agg_adj, Wt_adj, agg_g, Wt_g, xv_bf, Wt_sum, 3,
        bsum, out_var, stats, stats + 128);
    gemm_fused<<<(Ncon + 127) / 128, 256, 0, stream>>>(Ncon,
        agg_t, Wt_t, xc_bf, Wt_root_t, nullptr, nullptr, 2,
        b_t, out_con, stats + 256, stats + 384);

    // 7: fused normalize+relu+finalize over the contiguous [out_var | out_con] buffer
    {
        long nvecVar = (long)Nvar * 32;
        long nvecTot = (long)(Nvar + Ncon) * 32;
        norm_relu_fin<<<(int)((nvecTot + 255) / 256), 256, 0, stream>>>(
            out_var, nvecVar, nvecTot, stats,
            gnw_v, gnb_v, gnms_v, gnw_c, gnb_c, gnms_c, Nvar, Ncon);
    }
}

// Round 9
// 680.328 us; speedup vs baseline: 1.6294x; 1.1093x over previous
//
#include <hip/hip_runtime.h>
#include <hip/hip_bf16.h>

#define D 128
#define CAPB 2048     // CSR capacity per 256-dst bin (mean ~1300; ovf fallback exact)
#define MAXBINS 4096  // LDS bin-counter capacity (harness: ~1955 bins)

typedef __attribute__((ext_vector_type(8))) short bf16x8;
typedef __attribute__((ext_vector_type(4))) float f32x4;

__device__ __forceinline__ void atomAddF(float* p, float v) { unsafeAtomicAdd(p, v); }

__device__ __forceinline__ unsigned short f2bf(float f) {
    __hip_bfloat16 h = __float2bfloat16(f);
    return *reinterpret_cast<unsigned short*>(&h);
}
__device__ __forceinline__ float bf2f(unsigned int u16) {
    unsigned int x = u16 << 16;
    return *reinterpret_cast<float*>(&x);
}
// acc += ab.lo_bf16 * w.lo_bf16 + ab.hi_bf16 * w.hi_bf16   (one VALU op for 2 values)
__device__ __forceinline__ void dot2bf(float& acc, unsigned int ab, unsigned int w) {
    asm("v_dot2_f32_bf16 %0, %1, %2, %0" : "+v"(acc) : "v"(ab), "v"(w));
}
// dst = (bf16(lo), bf16(hi)) packed, RNE — 1 op vs 2 software-RNE sequences
__device__ __forceinline__ unsigned int pk_bf16(float lo, float hi) {
    unsigned int r;
    asm("v_cvt_pk_bf16_f32 %0, %1, %2" : "=v"(r) : "v"(lo), "v"(hi));
    return r;
}

// ---------------- fused: weights-prep + zero-region + cast fp32->bf16 (x3) ----------------
__global__ void prep_cast_zero(const float* __restrict__ Wra, const float* __restrict__ Wrg,
                               const float* __restrict__ Wrt, const float* __restrict__ Wroot_t,
                               const float* __restrict__ Wroot_a, const float* __restrict__ Wroot_g,
                               const float* __restrict__ ba, const float* __restrict__ bg,
                               unsigned short* __restrict__ Wt_adj, unsigned short* __restrict__ Wt_g,
                               unsigned short* __restrict__ Wt_t, unsigned short* __restrict__ Wt_root_t,
                               unsigned short* __restrict__ Wt_sum, float* __restrict__ bsum,
                               unsigned int* __restrict__ zbase, long zwords,
                               const float* __restrict__ xa, long n4a,
                               const float* __restrict__ xb, long n4b,
                               const float* __restrict__ xc, long n4c,
                               unsigned short* __restrict__ oa,
                               unsigned short* __restrict__ ob,
                               unsigned short* __restrict__ oc) {
    long gid = (long)blockIdx.x * blockDim.x + threadIdx.x;
    if (gid < D * D) {
        int i = (int)gid;
        int k = i >> 7, n = i & 127;
        int ti = n * D + k;
        Wt_adj[ti]    = f2bf(Wra[i]);
        Wt_g[ti]      = f2bf(Wrg[i]);
        Wt_t[ti]      = f2bf(Wrt[i]);
        Wt_root_t[ti] = f2bf(Wroot_t[i]);
        Wt_sum[ti]    = f2bf(Wroot_a[i] + Wroot_g[i]);
        if (i < D) bsum[i] = ba[i] + bg[i];
        return;
    }
    gid -= D * D;
    if (gid < zwords) { zbase[gid] = 0u; return; }
    gid -= zwords;
    const float* in; unsigned short* out; long li;
    if (gid < n4a)                 { in = xa; out = oa; li = gid; }
    else if (gid < n4a + n4b)      { in = xb; out = ob; li = gid - n4a; }
    else if (gid < n4a + n4b + n4c){ in = xc; out = oc; li = gid - n4a - n4b; }
    else return;
    float4 v = ((const float4*)in)[li];
    ushort4 o;
    o.x = f2bf(v.x); o.y = f2bf(v.y); o.z = f2bf(v.z); o.w = f2bf(v.w);
    ((ushort4*)out)[li] = o;
}

// ---------------- pass 1: LDS-aggregated binning ----------------
__launch_bounds__(256)
__global__ void binscatter3(const int* __restrict__ s0, const int* __restrict__ d0, int E0,
                            const int* __restrict__ s1, const int* __restrict__ d1, int E1,
                            const int* __restrict__ s2, const int* __restrict__ d2, int E2,
                            int nbV, int totBins,
                            unsigned int* __restrict__ pairs, int* __restrict__ gbincnt,
                            int* __restrict__ o0, int* __restrict__ o1, int* __restrict__ o2,
                            int* __restrict__ ovf_cnt) {
    __shared__ int lb[MAXBINS];
    const int t = threadIdx.x;
    const long Etot = (long)E0 + E1 + E2;
    const long chunk = (Etot + gridDim.x - 1) / gridDim.x;
    const long start = (long)blockIdx.x * chunk;
    long end = start + chunk; if (end > Etot) end = Etot;

    for (int b = t; b < totBins; b += 256) lb[b] = 0;
    __syncthreads();

    for (long e = start + t; e < end; e += 256) {
        int bidx;
        if (e < E0)                    bidx = (d0[e] >> 8);
        else if (e < (long)E0 + E1)    bidx = nbV + (d1[e - E0] >> 8);
        else                           bidx = 2 * nbV + (d2[e - E0 - E1] >> 8);
        atomicAdd(&lb[bidx], 1);                 // LDS atomic: cheap
    }
    __syncthreads();
    for (int b = t; b < totBins; b += 256) {
        int c = lb[b];
        lb[b] = (c > 0) ? atomicAdd(&gbincnt[b], c) : 0;   // reserve range; lb now = base
    }
    __syncthreads();
    for (long e = start + t; e < end; e += 256) {
        int s, d, le, bidx; int* ovf; int* oc;
        if (e < E0)                 { le = (int)e;             s = s0[le]; d = d0[le]; bidx = (d >> 8);           ovf = o0; oc = ovf_cnt +  0; }
        else if (e < (long)E0 + E1) { le = (int)(e - E0);      s = s1[le]; d = d1[le]; bidx = nbV + (d >> 8);     ovf = o1; oc = ovf_cnt + 16; }
        else                        { le = (int)(e - E0 - E1); s = s2[le]; d = d2[le]; bidx = 2 * nbV + (d >> 8); ovf = o2; oc = ovf_cnt + 32; }
        int slot = atomicAdd(&lb[bidx], 1);      // LDS cursor (base + local order)
        if (slot < CAPB) pairs[(long)bidx * CAPB + slot] = ((unsigned int)s << 8) | (unsigned int)(d & 255);
        else             ovf[atomicAdd(oc, 1)] = le;          // exact fallback (never hit w/ uniform dsts)
    }
}

// ---------------- pass 2: per-bin CSR build (LDS histogram + scan + scatter) ----------------
__launch_bounds__(256)
__global__ void build_csr(int nbV, int Nvar, int Ncon,
                          const unsigned int* __restrict__ pairs, const int* __restrict__ bincnt,
                          unsigned int* __restrict__ csr, unsigned int* __restrict__ rowinfo) {
    const int b = blockIdx.x;
    int N, dstBase, infoBase;
    if (b < nbV)          { N = Nvar; dstBase = b * 256;             infoBase = 0; }
    else if (b < 2 * nbV) { N = Nvar; dstBase = (b - nbV) * 256;     infoBase = Nvar; }
    else                  { N = Ncon; dstBase = (b - 2 * nbV) * 256; infoBase = 2 * Nvar; }

    int n = bincnt[b]; if (n > CAPB) n = CAPB;
    const long base = (long)b * CAPB;
    __shared__ int hist[256], scan[256], cur[256];
    const int t = threadIdx.x;
    hist[t] = 0;
    __syncthreads();
    for (int i = t; i < n; i += 256) atomicAdd(&hist[pairs[base + i] & 255], 1);
    __syncthreads();
    scan[t] = hist[t];
    __syncthreads();
    for (int off = 1; off < 256; off <<= 1) {
        int u = (t >= off) ? scan[t - off] : 0;
        __syncthreads();
        scan[t] += u;
        __syncthreads();
    }
    const int excl = scan[t] - hist[t];
    cur[t] = excl;
    if (dstBase + t < N)
        rowinfo[infoBase + dstBase + t] = ((unsigned int)excl << 16) | (unsigned int)hist[t];
    __syncthreads();
    for (int i = t; i < n; i += 256) {
        unsigned int pr = pairs[base + i];
        int slot = atomicAdd(&cur[pr & 255], 1);   // LDS atomic
        csr[base + slot] = pr >> 8;                 // src index
    }
}

// ---------------- pass 3: pull-aggregate from CSR — 4 dst rows per wave ----------------
// Each 16-lane quarter owns ONE dst row entirely (16 lanes x uint4 = 128 cols):
// no cross-quarter reduction tail, no lane<16 pack, direct per-lane store.
// Inner: 4 edges/step (4 shfl + 4 uint4 loads in flight), perm+dot2 accumulate with
// exact per-edge validity weights (short rows ride along with weight 0).
__launch_bounds__(256)
__global__ void pull_csr3(int Nvar, int Ncon, int nbV,
                          const unsigned short* __restrict__ xv, const unsigned short* __restrict__ xr,
                          const unsigned int* __restrict__ csr, const unsigned int* __restrict__ rowinfo,
                          const int* __restrict__ bincnt,
                          const int* __restrict__ s0, const int* __restrict__ d0, const int* __restrict__ o0,
                          const int* __restrict__ s1, const int* __restrict__ d1, const int* __restrict__ o1,
                          const int* __restrict__ s2, const int* __restrict__ d2, const int* __restrict__ o2,
                          const int* __restrict__ ovf_cnt,
                          unsigned short* __restrict__ agg_adj, unsigned short* __restrict__ agg_g,
                          unsigned short* __restrict__ agg_t) {
    const int tx = threadIdx.x;
    const int lane = tx & 63;
    const int ql = lane & 15;            // column group: cols [ql*8 .. ql*8+7]
    const int sl = lane & 48;            // quarter base lane (q*16)
    const long colOff = (long)ql * 8;

    const long tot = 2L * Nvar + Ncon;
    const long wv = ((long)blockIdx.x * blockDim.x + tx) >> 6;
    long r = wv * 4 + (lane >> 4);       // this quarter's dst row (global id)
    const bool active = r < tot;
    if (!active) r = tot - 1;            // clamp for safe addressing; store guarded

    // per-lane graph selection (uniform within quarter)
    const bool g1 = (r >= Nvar) && (r < 2L * Nvar);
    const bool g2 = (r >= 2L * Nvar);
    const unsigned short* y = g1 ? xr : xv;
    const int wid = (int)(r - (g1 ? (long)Nvar : 0) - (g2 ? 2L * Nvar : 0));
    const int infoBase = g1 ? Nvar : (g2 ? 2 * Nvar : 0);
    const long binBase = g1 ? nbV : (g2 ? 2L * nbV : 0);
    unsigned short* agg = g1 ? agg_g : (g2 ? agg_t : agg_adj);

    const unsigned int info = rowinfo[infoBase + wid];
    const int mc = active ? (int)(info & 0xffffu) : 0;
    const long b = binBase + (wid >> 8);
    const long cbase = b * CAPB + (long)(info >> 16);

    float a0 = 0.f, a1 = 0.f, a2 = 0.f, a3 = 0.f, a4 = 0.f, a5 = 0.f, a6 = 0.f, a7 = 0.f;

    for (int base = 0; __any(base < mc); base += 16) {
        int idx = (base + ql < mc) ? (int)csr[cbase + base + ql] : 0;
        for (int jj = 0; jj < 16; jj += 4) {
            const int e = base + jj;
            if (!__any(e < mc)) break;
            int i0 = __shfl(idx, sl + jj + 0, 64);   // edge e of OWN quarter's row
            int i1 = __shfl(idx, sl + jj + 1, 64);
            int i2 = __shfl(idx, sl + jj + 2, 64);
            int i3 = __shfl(idx, sl + jj + 3, 64);
            uint4 r0 = *(const uint4*)(y + (long)i0 * D + colOff);
            uint4 r1 = *(const uint4*)(y + (long)i1 * D + colOff);
            uint4 r2 = *(const uint4*)(y + (long)i2 * D + colOff);
            uint4 r3 = *(const uint4*)(y + (long)i3 * D + colOff);
            unsigned int w01 = ((e     < mc) ? 0x3F80u : 0u) | ((e + 1 < mc) ? 0x3F800000u : 0u);
            unsigned int w23 = ((e + 2 < mc) ? 0x3F80u : 0u) | ((e + 3 < mc) ? 0x3F800000u : 0u);
            unsigned int p;
            // perm 0x01000504: (src0.lo_bf16, src1.lo_bf16); 0x03020706: high halves
            p = __builtin_amdgcn_perm(r0.x, r1.x, 0x01000504u); dot2bf(a0, p, w01);
            p = __builtin_amdgcn_perm(r2.x, r3.x, 0x01000504u); dot2bf(a0, p, w23);
            p = __builtin_amdgcn_perm(r0.x, r1.x, 0x03020706u); dot2bf(a1, p, w01);
            p = __builtin_amdgcn_perm(r2.x, r3.x, 0x03020706u); dot2bf(a1, p, w23);
            p = __builtin_amdgcn_perm(r0.y, r1.y, 0x01000504u); dot2bf(a2, p, w01);
            p = __builtin_amdgcn_perm(r2.y, r3.y, 0x01000504u); dot2bf(a2, p, w23);
            p = __builtin_amdgcn_perm(r0.y, r1.y, 0x03020706u); dot2bf(a3, p, w01);
            p = __builtin_amdgcn_perm(r2.y, r3.y, 0x03020706u); dot2bf(a3, p, w23);
            p = __builtin_amdgcn_perm(r0.z, r1.z, 0x01000504u); dot2bf(a4, p, w01);
            p = __builtin_amdgcn_perm(r2.z, r3.z, 0x01000504u); dot2bf(a4, p, w23);
            p = __builtin_amdgcn_perm(r0.z, r1.z, 0x03020706u); dot2bf(a5, p, w01);
            p = __builtin_amdgcn_perm(r2.z, r3.z, 0x03020706u); dot2bf(a5, p, w23);
            p = __builtin_amdgcn_perm(r0.w, r1.w, 0x01000504u); dot2bf(a6, p, w01);
            p = __builtin_amdgcn_perm(r2.w, r3.w, 0x01000504u); dot2bf(a6, p, w23);
            p = __builtin_amdgcn_perm(r0.w, r1.w, 0x03020706u); dot2bf(a7, p, w01);
            p = __builtin_amdgcn_perm(r2.w, r3.w, 0x03020706u); dot2bf(a7, p, w23);
        }
    }

    if (active && bincnt[b] > CAPB) {    // rare: bin overflowed -> exact scan of ovf list
        const int* srcp = g1 ? s1 : (g2 ? s2 : s0);
        const int* dstp = g1 ? d1 : (g2 ? d2 : d0);
        const int* ovf  = g1 ? o1 : (g2 ? o2 : o0);
        const int oc = ovf_cnt[g1 ? 16 : (g2 ? 32 : 0)];
        for (int i = 0; i < oc; ++i) {
            int e = ovf[i];
            if (dstp[e] == wid) {        // every lane of the quarter adds its own cols
                int s = srcp[e];
                uint4 rr = *(const uint4*)(y + (long)s * D + colOff);
                a0 += bf2f(rr.x & 0xffffu); a1 += bf2f(rr.x >> 16);
                a2 += bf2f(rr.y & 0xffffu); a3 += bf2f(rr.y >> 16);
                a4 += bf2f(rr.z & 0xffffu); a5 += bf2f(rr.z >> 16);
                a6 += bf2f(rr.w & 0xffffu); a7 += bf2f(rr.w >> 16);
            }
        }
    }

    if (active) {
        uint4 o;
        o.x = pk_bf16(a0, a1);
        o.y = pk_bf16(a2, a3);
        o.z = pk_bf16(a4, a5);
        o.w = pk_bf16(a6, a7);
        *(uint4*)(agg + (long)wid * D + colOff) = o;
    }
}

// ---------------- fused MFMA GEMM, LDS-staged (m97-style 2-phase) — R2-verbatim ----------------
__launch_bounds__(256, 4)
__global__ void gemm_fused(int N,
                           const unsigned short* __restrict__ A0, const unsigned short* __restrict__ Wt0,
                           const unsigned short* __restrict__ A1, const unsigned short* __restrict__ Wt1,
                           const unsigned short* __restrict__ A2, const unsigned short* __restrict__ Wt2,
                           int nTerms,
                           const float* __restrict__ bias, float* __restrict__ out,
                           float* __restrict__ gsum, float* __restrict__ gsq) {
    __shared__ unsigned short lds[2][8192];   // per buf: A slots 0..511 (8KB), B slots at +4096 (8KB)
    __shared__ float sstat[256];
    const int tx = threadIdx.x;
    sstat[tx] = 0.f;

    const int wave = tx >> 6, lane = tx & 63;
    const int quad = lane >> 4, l16 = lane & 15;
    const int row0 = blockIdx.x * 128;

    const int sA0 = tx, sA1 = tx + 256;
    const int rS0 = sA0 >> 2, qS0 = (sA0 & 3) ^ ((sA0 >> 4) & 3);
    const int rS1 = sA1 >> 2, qS1 = (sA1 & 3) ^ ((sA1 >> 4) & 3);
    long gr0 = (long)row0 + rS0; if (gr0 >= N) gr0 = N - 1;
    long gr1 = (long)row0 + rS1; if (gr1 >= N) gr1 = N - 1;

    f32x4 acc[2][8];
#pragma unroll
    for (int rt = 0; rt < 2; ++rt)
#pragma unroll
        for (int ct = 0; ct < 8; ++ct)
#pragma unroll
            for (int i = 0; i < 4; ++i) acc[rt][ct][i] = 0.f;

    auto stage = [&](int s, int bb) {
        const int t = s >> 2;
        const int k0 = (s & 3) * 32;
        const unsigned short* A = (t == 0) ? A0 : ((t == 1) ? A1 : A2);
        const unsigned short* W = (t == 0) ? Wt0 : ((t == 1) ? Wt1 : Wt2);
        __builtin_amdgcn_global_load_lds(
            (const __attribute__((address_space(1))) unsigned int*)(A + gr0 * D + k0 + qS0 * 8),
            (__attribute__((address_space(3))) unsigned int*)(&lds[bb][sA0 * 8]), 16, 0, 0);
        __builtin_amdgcn_global_load_lds(
            (const __attribute__((address_space(1))) unsigned int*)(A + gr1 * D + k0 + qS1 * 8),
            (__attribute__((address_space(3))) unsigned int*)(&lds[bb][sA1 * 8]), 16, 0, 0);
        __builtin_amdgcn_global_load_lds(
            (const __attribute__((address_space(1))) unsigned int*)(W + (long)rS0 * D + k0 + qS0 * 8),
            (__attribute__((address_space(3))) unsigned int*)(&lds[bb][4096 + sA0 * 8]), 16, 0, 0);
        __builtin_amdgcn_global_load_lds(
            (const __attribute__((address_space(1))) unsigned int*)(W + (long)rS1 * D + k0 + qS1 * 8),
            (__attribute__((address_space(3))) unsigned int*)(&lds[bb][4096 + sA1 * 8]), 16, 0, 0);
    };

    const int xq = (l16 >> 2) & 3;
    const int qx = quad ^ xq;

    auto compute = [&](int cb) {
        const int slotA0 = (wave * 32 + l16) * 4 + qx;
        const int slotA1 = (wave * 32 + 16 + l16) * 4 + qx;
        bf16x8 a0 = *(const bf16x8*)&lds[cb][slotA0 * 8];
        bf16x8 a1 = *(const bf16x8*)&lds[cb][slotA1 * 8];
#pragma unroll
        for (int ct = 0; ct < 8; ++ct) {
            const int slotB = (ct * 16 + l16) * 4 + qx;
            bf16x8 b = *(const bf16x8*)&lds[cb][4096 + slotB * 8];
            acc[0][ct] = __builtin_amdgcn_mfma_f32_16x16x32_bf16(a0, b, acc[0][ct], 0, 0, 0);
            acc[1][ct] = __builtin_amdgcn_mfma_f32_16x16x32_bf16(a1, b, acc[1][ct], 0, 0, 0);
        }
    };

    const int nsteps = nTerms * 4;
    stage(0, 0);
    __syncthreads();
    for (int s = 0; s < nsteps; ++s) {
        const int cb = s & 1;
        if (s + 1 < nsteps) stage(s + 1, cb ^ 1);
        compute(cb);
        __syncthreads();
    }

    float bv[8];
#pragma unroll
    for (int ct = 0; ct < 8; ++ct) bv[ct] = bias[ct * 16 + l16];

    float psum[8], psq[8];
#pragma unroll
    for (int ct = 0; ct < 8; ++ct) { psum[ct] = 0.f; psq[ct] = 0.f; }

#pragma unroll
    for (int rt = 0; rt < 2; ++rt)
#pragma unroll
        for (int i = 0; i < 4; ++i) {
            int row = row0 + wave * 32 + rt * 16 + quad * 4 + i;
            if (row < N) {
#pragma unroll
                for (int ct = 0; ct < 8; ++ct) {
                    float v = acc[rt][ct][i] + bv[ct];
                    out[(size_t)row * D + ct * 16 + l16] = v;
                    psum[ct] += v;
                    psq[ct] += v * v;
                }
            }
        }

#pragma unroll
    for (int ct = 0; ct < 8; ++ct) {
        atomicAdd(&sstat[ct * 16 + l16], psum[ct]);
        atomicAdd(&sstat[128 + ct * 16 + l16], psq[ct]);
    }
    __syncthreads();
    if (tx < 128) {
        atomAddF(&gsum[tx], sstat[tx]);
        atomAddF(&gsq[tx], sstat[128 + tx]);
    }
}

// ---------------- fused normalize+relu with per-block stats finalization ----------------
__global__ void norm_relu_fin(float* __restrict__ buf,
                              long nvecVar, long nvecTot,
                              const float* __restrict__ stats,
                              const float* __restrict__ wv, const float* __restrict__ bv, const float* __restrict__ msv,
                              const float* __restrict__ wc, const float* __restrict__ bc, const float* __restrict__ msc,
                              int Nvar, int Ncon) {
    __shared__ float ss[512];   // [0:128) scale_var [128:256) shift_var [256:384) scale_con [384:512) shift_con
    const int t = threadIdx.x;
    {
        const int col = t & 127;
        const bool isv = t < 128;
        const float n = isv ? (float)Nvar : (float)Ncon;
        const float* st = stats + (isv ? 0 : 256);
        const float mu = st[col] / n;
        const float ex2 = st[128 + col] / n;
        const float ms = (isv ? msv : msc)[col];
        const float var = ex2 - 2.f * ms * mu * mu + ms * ms * mu * mu;
        const float istd = rsqrtf(var + 1e-5f);
        const float sc = (isv ? wv : wc)[col] * istd;
        ss[(isv ? 0 : 256) + col] = sc;
        ss[(isv ? 128 : 384) + col] = (isv ? bv : bc)[col] - sc * ms * mu;
    }
    __syncthreads();
    long i = (long)blockIdx.x * blockDim.x + t;
    if (i >= nvecTot) return;
    const int base = (i < nvecVar) ? 0 : 256;
    const int q = ((int)i & 31) * 4;
    float4 v = *(float4*)(buf + i * 4);
    float4 o;
    o.x = fmaxf(0.f, v.x * ss[base + q + 0] + ss[base + 128 + q + 0]);
    o.y = fmaxf(0.f, v.y * ss[base + q + 1] + ss[base + 128 + q + 1]);
    o.z = fmaxf(0.f, v.z * ss[base + q + 2] + ss[base + 128 + q + 2]);
    o.w = fmaxf(0.f, v.w * ss[base + q + 3] + ss[base + 128 + q + 3]);
    *(float4*)(buf + i * 4) = o;
}

extern "C" void kernel_launch(void* const* d_in, const int* in_sizes, int n_in,
                              void* d_out, int out_size, void* d_ws, size_t ws_size,
                              hipStream_t stream) {
    const float* x_var = (const float*)d_in[0];
    const float* x_con = (const float*)d_in[1];
    const float* x_reg = (const float*)d_in[2];
    const int* src_adj = (const int*)d_in[3];
    const int* dst_adj = (const int*)d_in[4];
    const int* src_t   = (const int*)d_in[5];
    const int* dst_t   = (const int*)d_in[6];
    const int* src_g   = (const int*)d_in[7];
    const int* dst_g   = (const int*)d_in[8];
    const float* W_rel_adj  = (const float*)d_in[9];
    const float* b_adj      = (const float*)d_in[10];
    const float* W_root_adj = (const float*)d_in[11];
    const float* W_rel_t    = (const float*)d_in[12];
    const float* b_t        = (const float*)d_in[13];
    const float* W_root_t   = (const float*)d_in[14];
    const float* W_rel_g    = (const float*)d_in[15];
    const float* b_g        = (const float*)d_in[16];
    const float* W_root_g   = (const float*)d_in[17];
    const float* gnw_v  = (const float*)d_in[18];
    const float* gnb_v  = (const float*)d_in[19];
    const float* gnms_v = (const float*)d_in[20];
    const float* gnw_c  = (const float*)d_in[21];
    const float* gnb_c  = (const float*)d_in[22];
    const float* gnms_c = (const float*)d_in[23];

    const int Nvar = in_sizes[0] / D;
    const int Ncon = in_sizes[1] / D;
    const int Nreg = in_sizes[2] / D;
    const int Eadj = in_sizes[3];
    const int Et   = in_sizes[5];
    const int Eg   = in_sizes[7];

    const int nbV = (Nvar + 255) >> 8;     // bins per var-dst graph (adj, groups)
    const int nbC = (Ncon + 255) >> 8;     // bins for touch
    const int totBins = 2 * nbV + nbC;

    // ---- workspace layout (large blocks first, all 256B-aligned) ----
    char* p = (char*)d_ws;
    unsigned short* xv_bf = (unsigned short*)p; p += (size_t)Nvar * D * 2;
    unsigned short* xc_bf = (unsigned short*)p; p += (size_t)Ncon * D * 2;
    unsigned short* xr_bf = (unsigned short*)p; p += (size_t)Nreg * D * 2;
    unsigned short* agg_adj = (unsigned short*)p; p += (size_t)Nvar * D * 2;
    unsigned short* agg_g   = (unsigned short*)p; p += (size_t)Nvar * D * 2;
    unsigned short* agg_t   = (unsigned short*)p; p += (size_t)Ncon * D * 2;
    unsigned int* pairs = (unsigned int*)p; p += (size_t)totBins * CAPB * 4;
    unsigned int* csr   = (unsigned int*)p; p += (size_t)totBins * CAPB * 4;
    unsigned int* rowinfo = (unsigned int*)p; p += (size_t)(2 * Nvar + Ncon) * 4;
    int* ovf0 = (int*)p; p += (size_t)Eadj * 4;
    int* ovf1 = (int*)p; p += (size_t)Eg * 4;
    int* ovf2 = (int*)p; p += (size_t)Et * 4;
    unsigned short* Wt_adj    = (unsigned short*)p; p += D * D * 2;
    unsigned short* Wt_g      = (unsigned short*)p; p += D * D * 2;
    unsigned short* Wt_t      = (unsigned short*)p; p += D * D * 2;
    unsigned short* Wt_root_t = (unsigned short*)p; p += D * D * 2;
    unsigned short* Wt_sum    = (unsigned short*)p; p += D * D * 2;
    float* bsum  = (float*)p; p += D * 4;
    // ---- contiguous zero region: stats(512f) + ovf_cnt(64i) + bincnt(totBins) ----
    char* zbase = p;
    float* stats   = (float*)p; p += 512 * 4;
    int* ovf_cnt   = (int*)p;   p += 64 * 4;         // [0],[16],[32] used
    int* bincnt    = (int*)p;   p += (size_t)totBins * 4;
    const long zwords = (long)(p - zbase) / 4;

    float* out_var = (float*)d_out;
    float* out_con = out_var + (size_t)Nvar * D;

    // 1: fused weights-prep + zero + casts
    {
        long n4v = (long)Nvar * 32, n4c = (long)Ncon * 32, n4r = (long)Nreg * 32;
        long tot = (long)D * D + zwords + n4v + n4c + n4r;
        prep_cast_zero<<<(int)((tot + 255) / 256), 256, 0, stream>>>(
            W_rel_adj, W_rel_g, W_rel_t, W_root_t, W_root_adj, W_root_g, b_adj, b_g,
            Wt_adj, Wt_g, Wt_t, Wt_root_t, Wt_sum, bsum,
            (unsigned int*)zbase, zwords,
            x_var, n4v, x_con, n4c, x_reg, n4r, xv_bf, xc_bf, xr_bf);
    }

    // 2: LDS-aggregated bin+scatter (graph order: adj, groups, touch)
    binscatter3<<<128, 256, 0, stream>>>(
        src_adj, dst_adj, Eadj,
        src_g,   dst_g,   Eg,
        src_t,   dst_t,   Et,
        nbV, totBins, pairs, bincnt, ovf0, ovf1, ovf2, ovf_cnt);

    // 3: per-bin CSR build
    build_csr<<<totBins, 256, 0, stream>>>(nbV, Nvar, Ncon, pairs, bincnt, csr, rowinfo);

    // 4: pull-aggregate from CSR (4 rows per wave)
    {
        long rows = (long)2 * Nvar + Ncon;
        long T = ((rows + 3) / 4) * 64;
        pull_csr3<<<(int)((T + 255) / 256), 256, 0, stream>>>(
            Nvar, Ncon, nbV, xv_bf, xr_bf,
            csr, rowinfo, bincnt,
            src_adj, dst_adj, ovf0,
            src_g,   dst_g,   ovf1,
            src_t,   dst_t,   ovf2,
            ovf_cnt, agg_adj, agg_g, agg_t);
    }

    // 5,6: GEMMs (R2-verbatim structure)
    gemm_fused<<<(Nvar + 127) / 128, 256, 0, stream>>>(Nvar,
        agg_adj, Wt_adj, agg_g, Wt_g, xv_bf, Wt_sum, 3,
        bsum, out_var, stats, stats + 128);
    gemm_fused<<<(Ncon + 127) / 128, 256, 0, stream>>>(Ncon,
        agg_t, Wt_t, xc_bf, Wt_root_t, nullptr, nullptr, 2,
        b_t, out_con, stats + 256, stats + 384);

    // 7: fused normalize+relu+finalize over the contiguous [out_var | out_con] buffer
    {
        long nvecVar = (long)Nvar * 32;
        long nvecTot = (long)(Nvar + Ncon) * 32;
        norm_relu_fin<<<(int)((nvecTot + 255) / 256), 256, 0, stream>>>(
            out_var, nvecVar, nvecTot, stats,
            gnw_v, gnb_v, gnms_v, gnw_c, gnb_c, gnms_c, Nvar, Ncon);
    }
}